// Round 8
// baseline (312.095 us; speedup 1.0000x reference)
//
#include <hip/hip_runtime.h>
#include <stdint.h>

typedef unsigned short u16;
typedef u16   u16x4    __attribute__((ext_vector_type(4)));
typedef u16   u16x8    __attribute__((ext_vector_type(8)));
typedef u16x8 u16x8_ma __attribute__((may_alias));
typedef __bf16 bf16x8  __attribute__((ext_vector_type(8)));
typedef float f32x4    __attribute__((ext_vector_type(4)));
typedef f32x4 f32x4_ma __attribute__((may_alias));

#define EMB    1024
#define NHEAD  16
#define HD     64
#define SEQ    2048
#define NBATCH 2
#define ROWS   (NBATCH*SEQ)   // 4096
#define SATT   72             // attn K/P LDS row stride (r6-measured)

__device__ __forceinline__ u16 f2b(float f) {
  uint32_t u; __builtin_memcpy(&u, &f, 4);
  u = u + 0x7fffu + ((u >> 16) & 1u);
  return (u16)(u >> 16);
}
__device__ __forceinline__ u16x8 ld8(const u16* p) { return *(const u16x8_ma*)p; }
__device__ __forceinline__ void  st8(u16* p, u16x8 v) { *(u16x8_ma*)p = v; }
__device__ __forceinline__ bf16x8 asbf(u16x8 v) {
  union { u16x8 u; bf16x8 b; } c; c.u = v; return c.b;
}
// async global->LDS, 16B/lane; LDS dest = wave-uniform base + lane*16 (m97).
__device__ __forceinline__ void async_cp16(const u16* g, u16* l) {
  __builtin_amdgcn_global_load_lds(
      (const __attribute__((address_space(1))) void*)g,
      (__attribute__((address_space(3))) void*)l, 16, 0, 0);
}

// ---------------------------------------------------------------------------
// Fused f32 -> bf16 conversion: x (4096 blocks) + 4 weights (1024 each).
// ---------------------------------------------------------------------------
__global__ __launch_bounds__(256) void cvt_all(
    const float* __restrict__ x,
    const float* __restrict__ w0, const float* __restrict__ w1,
    const float* __restrict__ w2, const float* __restrict__ w3,
    u16* __restrict__ xd, u16* __restrict__ d0, u16* __restrict__ d1,
    u16* __restrict__ d2, u16* __restrict__ d3)
{
  int bid = blockIdx.x;
  const float* s; u16* d; int off;
  if (bid < 4096) { s = x; d = xd; off = bid; }
  else {
    int t = bid - 4096; int m = t >> 10; off = t & 1023;
    switch (m) {
      case 0: s = w0; d = d0; break;
      case 1: s = w1; d = d1; break;
      case 2: s = w2; d = d2; break;
      default: s = w3; d = d3; break;
    }
  }
  size_t i = ((size_t)off * 256 + threadIdx.x) * 4;
  f32x4 v = *(const f32x4_ma*)(s + i);
  u16x4 o;
  #pragma unroll
  for (int j = 0; j < 4; j++) o[j] = f2b(v[j]);
  *(u16x4*)(d + i) = o;
}

// ---------------------------------------------------------------------------
// 128x128 GEMM core, m97 structure (global_load_lds width-16, stride-32 LDS).
// AMODE=0: A row-major. AMODE=1: A in [N,16,L,64]. B n-major.
// ---------------------------------------------------------------------------
template<int AMODE>
__device__ __forceinline__ void gemm_acc_128x128(
    const u16* __restrict__ A, const u16* __restrict__ B,
    int m0, int n0, u16* As, u16* Bs, f32x4 acc[4][4])
{
  const int tid  = threadIdx.x;
  const int lane = tid & 63;
  const int wave = tid >> 6;
  const int wm   = (wave >> 1) * 64;
  const int wn   = (wave & 1) * 64;
  const int ar   = tid >> 2;
  const int ac   = (tid & 3) * 8;
  const int lm   = lane & 15;
  const int lk   = (lane >> 4) * 8;

  #pragma unroll
  for (int i = 0; i < 4; i++)
    #pragma unroll
    for (int j = 0; j < 4; j++)
      #pragma unroll
      for (int e = 0; e < 4; e++) acc[i][j][e] = 0.f;

  for (int k0 = 0; k0 < EMB; k0 += 32) {
    size_t a0off, a1off;
    if (AMODE == 0) {
      a0off = (size_t)(m0 + ar)      * EMB + k0 + ac;
      a1off = (size_t)(m0 + ar + 64) * EMB + k0 + ac;
    } else {
      int col = k0 + ac, h = col >> 6, d = col & 63;
      int r0 = m0 + ar, r1 = m0 + ar + 64;
      a0off = (((size_t)((r0 >> 11) * NHEAD + h)) * SEQ + (r0 & (SEQ-1))) * HD + d;
      a1off = (((size_t)((r1 >> 11) * NHEAD + h)) * SEQ + (r1 & (SEQ-1))) * HD + d;
    }
    __syncthreads();
    async_cp16(A + a0off, As + tid * 8);
    async_cp16(A + a1off, As + (tid + 256) * 8);
    async_cp16(B + (size_t)(n0 + ar)      * EMB + k0 + ac, Bs + tid * 8);
    async_cp16(B + (size_t)(n0 + ar + 64) * EMB + k0 + ac, Bs + (tid + 256) * 8);
    __syncthreads();

    bf16x8 af[4], bfr[4];
    #pragma unroll
    for (int i = 0; i < 4; i++)
      af[i] = asbf(ld8(As + (wm + i * 16 + lm) * 32 + lk));
    #pragma unroll
    for (int j = 0; j < 4; j++)
      bfr[j] = asbf(ld8(Bs + (wn + j * 16 + lm) * 32 + lk));
    #pragma unroll
    for (int i = 0; i < 4; i++)
      #pragma unroll
      for (int j = 0; j < 4; j++)
        acc[i][j] = __builtin_amdgcn_mfma_f32_16x16x32_bf16(af[i], bfr[j], acc[i][j], 0, 0, 0);
  }
}

// LN over the wave's 64-col head span + scatter to bf16 [N, Hdst, L, 64].
__device__ __forceinline__ void epilogue_scatter_ln(
    f32x4 acc[4][4], u16* dst, int m0, int n0, int head_base, int Hdst,
    const float* g, const float* b, int do_ln)
{
  const int lane = threadIdx.x & 63, wave = threadIdx.x >> 6;
  const int wm = (wave >> 1) * 64, wn = (wave & 1) * 64;
  const int lm = lane & 15, quad = lane >> 4;

  float gv[4], bv[4];
  #pragma unroll
  for (int j = 0; j < 4; j++) { gv[j] = g[j * 16 + lm]; bv[j] = b[j * 16 + lm]; }

  #pragma unroll
  for (int i = 0; i < 4; i++)
    #pragma unroll
    for (int r = 0; r < 4; r++) {
      float val[4];
      #pragma unroll
      for (int j = 0; j < 4; j++) val[j] = acc[i][j][r];
      if (do_ln) {
        float s = val[0] + val[1] + val[2] + val[3];
        #pragma unroll
        for (int o = 8; o >= 1; o >>= 1) s += __shfl_xor(s, o, 64);
        float mean = s * (1.f / 64.f);
        float ss = 0.f;
        #pragma unroll
        for (int j = 0; j < 4; j++) { val[j] -= mean; ss += val[j] * val[j]; }
        #pragma unroll
        for (int o = 8; o >= 1; o >>= 1) ss += __shfl_xor(ss, o, 64);
        float inv = rsqrtf(ss * (1.f / 64.f) + 1e-5f);
        #pragma unroll
        for (int j = 0; j < 4; j++) val[j] = val[j] * inv * gv[j] + bv[j];
      }
      int row = m0 + wm + i * 16 + quad * 4 + r;
      int bn = row >> 11, l = row & (SEQ - 1);
      #pragma unroll
      for (int j = 0; j < 4; j++) {
        int col = n0 + wn + j * 16 + lm;
        int hl = (col >> 6) - head_base, d = col & 63;
        dst[(((size_t)(bn * Hdst + hl)) * SEQ + l) * HD + d] = f2b(val[j]);
      }
    }
}

// Merged QKV projection: grid (8, 32, 3).
__global__ __launch_bounds__(256) void gemm_qkv(
    const u16* __restrict__ x,
    const u16* __restrict__ Wq, const u16* __restrict__ Wk, const u16* __restrict__ Wv,
    const float* __restrict__ gq, const float* __restrict__ bq,
    const float* __restrict__ gk, const float* __restrict__ bk,
    u16* __restrict__ qd, u16* __restrict__ kb, u16* __restrict__ vb)
{
  __shared__ __align__(16) u16 As[128 * 32];
  __shared__ __align__(16) u16 Bs[128 * 32];
  const u16* W; u16* dst; const float* g; const float* b; int ln;
  if (blockIdx.z == 0)      { W = Wq; dst = qd; g = gq; b = bq; ln = 1; }
  else if (blockIdx.z == 1) { W = Wk; dst = kb; g = gk; b = bk; ln = 1; }
  else                      { W = Wv; dst = vb; g = gq; b = bq; ln = 0; }
  const int m0 = blockIdx.y * 128, n0 = blockIdx.x * 128;
  f32x4 acc[4][4];
  gemm_acc_128x128<0>(x, W, m0, n0, As, Bs, acc);
  epilogue_scatter_ln(acc, dst, m0, n0, 0, NHEAD, g, b, ln);
}

// Fallback kernels for small-workspace multi-pass K/V.
__global__ __launch_bounds__(256) void gemm_q(
    const u16* __restrict__ x, const u16* __restrict__ Wq,
    const float* __restrict__ gq, const float* __restrict__ bq,
    u16* __restrict__ qd)
{
  __shared__ __align__(16) u16 As[128 * 32];
  __shared__ __align__(16) u16 Bs[128 * 32];
  const int m0 = blockIdx.y * 128, n0 = blockIdx.x * 128;
  f32x4 acc[4][4];
  gemm_acc_128x128<0>(x, Wq, m0, n0, As, Bs, acc);
  epilogue_scatter_ln(acc, qd, m0, n0, 0, NHEAD, gq, bq, 1);
}
__global__ __launch_bounds__(256) void gemm_kv(
    const u16* __restrict__ x,
    const u16* __restrict__ Wk, const u16* __restrict__ Wv,
    const float* __restrict__ gk, const float* __restrict__ bk,
    u16* __restrict__ k, u16* __restrict__ v, int head_lo, int hpp)
{
  __shared__ __align__(16) u16 As[128 * 32];
  __shared__ __align__(16) u16 Bs[128 * 32];
  const int m0 = blockIdx.y * 128, n0 = blockIdx.x * 128;
  const u16* W = (blockIdx.z == 0 ? Wk : Wv) + (size_t)head_lo * HD * EMB;
  u16* dst = (blockIdx.z == 0) ? k : v;
  f32x4 acc[4][4];
  gemm_acc_128x128<0>(x, W, m0, n0, As, Bs, acc);
  epilogue_scatter_ln(acc, dst, m0, n0, 0, hpp, gk, bk, blockIdx.z == 0);
}

// ---------------------------------------------------------------------------
// Flash causal attention, UNPAIRED, in place on qd. One 64-row q-tile per
// block, qt = 31 - blockIdx.x (longest dispatched first -> LPT balance).
// Single-buffered K/V LDS (26.6 KB -> 5 blocks/CU, launch_bounds(256,5));
// register prefetch of tile t+1 between the barriers hides global latency;
// cross-block TLP (20 waves/CU) hides the LDS roundtrip + barriers.
// r6-measured softmax internals (running max), SATT=72, Vts XOR swizzle.
// grid (32, hpp, NBATCH), block 256.
// ---------------------------------------------------------------------------
__global__ __launch_bounds__(256, 5) void attn(
    u16* qd, const u16* __restrict__ K, const u16* __restrict__ V,
    int head_lo, int hpp)
{
  __shared__ __align__(16) u16 Ks[64 * SATT];
  __shared__ __align__(16) u16 Vts[64 * 64];      // XOR-swizzled transpose
  __shared__ __align__(16) u16 Ps[4][16 * SATT];  // per-wave P strip

  const int qt = 31 - (int)blockIdx.x;            // longest first
  const int hl = blockIdx.y, n = blockIdx.z;
  const int tid = threadIdx.x, lane = tid & 63, wave = tid >> 6;
  const int lm = lane & 15, quad = lane >> 4, lk = quad * 8;
  u16* Qh = qd + ((size_t)(n * NHEAD + head_lo + hl)) * SEQ * HD;
  const u16* Kh = K + ((size_t)(n * hpp + hl)) * SEQ * HD;
  const u16* Vh = V + ((size_t)(n * hpp + hl)) * SEQ * HD;

  const int sr = tid >> 3;        // 0..31 (key)
  const int sc = (tid & 7) * 8;   // 0..56 (d base)
  const int vswz = tid & 7;

  // Q fragments in registers (loop-invariant): A[m=lm][k=quad*8+j (+32*ks)]
  bf16x8 aq[2];
  #pragma unroll
  for (int ks = 0; ks < 2; ++ks)
    aq[ks] = asbf(ld8(Qh + (size_t)(qt * 64 + wave * 16 + lm) * HD + ks * 32 + lk));

  // prefetch tile 0 into registers
  u16x8 kr0, kr1, vr0, vr1;
  kr0 = ld8(Kh + (size_t)(sr)      * HD + sc);
  kr1 = ld8(Kh + (size_t)(sr + 32) * HD + sc);
  vr0 = ld8(Vh + (size_t)(sr)      * HD + sc);
  vr1 = ld8(Vh + (size_t)(sr + 32) * HD + sc);

  f32x4 oacc[4];
  float m_i[4], l_i[4];
  #pragma unroll
  for (int j = 0; j < 4; j++)
    #pragma unroll
    for (int e = 0; e < 4; e++) oacc[j][e] = 0.f;
  #pragma unroll
  for (int r = 0; r < 4; r++) { m_i[r] = -1e30f; l_i[r] = 0.f; }

  u16* Pw = &Ps[wave][0];

  for (int t = 0; t <= qt; ++t) {
    __syncthreads();   // previous iteration's LDS reads complete
    st8(&Ks[sr * SATT + sc], kr0);
    st8(&Ks[(sr + 32) * SATT + sc], kr1);
    #pragma unroll
    for (int jj = 0; jj < 8; jj++) {
      int d = sc + jj;
      Vts[d * 64 + (((sr >> 3) ^ vswz) * 8) + (sr & 7)]        = vr0[jj];
      Vts[d * 64 + ((((sr + 32) >> 3) ^ vswz) * 8) + (sr & 7)] = vr1[jj];
    }
    if (t < qt) {   // issue loads for tile t+1 (land during compute)
      const size_t base = (size_t)(t + 1) * 64;
      kr0 = ld8(Kh + (base + sr)      * HD + sc);
      kr1 = ld8(Kh + (base + sr + 32) * HD + sc);
      vr0 = ld8(Vh + (base + sr)      * HD + sc);
      vr1 = ld8(Vh + (base + sr + 32) * HD + sc);
    }
    __syncthreads();   // tile ready

    // S = Q K^T : 16 q-rows x 64 keys per wave
    f32x4 s[4];
    #pragma unroll
    for (int j = 0; j < 4; j++)
      #pragma unroll
      for (int e = 0; e < 4; e++) s[j][e] = 0.f;
    #pragma unroll
    for (int ks = 0; ks < 2; ++ks)
      #pragma unroll
      for (int j = 0; j < 4; j++) {
        bf16x8 bk = asbf(ld8(&Ks[(j * 16 + lm) * SATT + ks * 32 + lk]));
        s[j] = __builtin_amdgcn_mfma_f32_16x16x32_bf16(aq[ks], bk, s[j], 0, 0, 0);
      }
    if (t == qt) {   // causal mask on the diagonal tile
      #pragma unroll
      for (int j = 0; j < 4; j++) {
        int col = t * 64 + j * 16 + lm;
        #pragma unroll
        for (int r = 0; r < 4; r++) {
          int row = qt * 64 + wave * 16 + quad * 4 + r;
          if (col > row) s[j][r] = -1e30f;
        }
      }
    }
    // online softmax (rows live across the quad's 16 lanes)
    float mnew[4], alpha[4], rsum[4];
    #pragma unroll
    for (int r = 0; r < 4; r++) {
      float mx = fmaxf(fmaxf(s[0][r], s[1][r]), fmaxf(s[2][r], s[3][r]));
      #pragma unroll
      for (int o = 8; o >= 1; o >>= 1) mx = fmaxf(mx, __shfl_xor(mx, o, 64));
      mnew[r] = fmaxf(m_i[r], mx);
      alpha[r] = __expf(m_i[r] - mnew[r]);
      m_i[r] = mnew[r];
      rsum[r] = 0.f;
    }
    #pragma unroll
    for (int j = 0; j < 4; j++)
      #pragma unroll
      for (int r = 0; r < 4; r++) {
        float pv = __expf(s[j][r] - mnew[r]);
        s[j][r] = pv;
        rsum[r] += pv;
      }
    #pragma unroll
    for (int r = 0; r < 4; r++) {
      #pragma unroll
      for (int o = 8; o >= 1; o >>= 1) rsum[r] += __shfl_xor(rsum[r], o, 64);
      l_i[r] = l_i[r] * alpha[r] + rsum[r];
    }
    #pragma unroll
    for (int j = 0; j < 4; j++)
      #pragma unroll
      for (int r = 0; r < 4; r++) oacc[j][r] *= alpha[r];

    // P: C-layout -> LDS (wave-private) -> A-layout
    #pragma unroll
    for (int j = 0; j < 4; j++)
      #pragma unroll
      for (int r = 0; r < 4; r++)
        Pw[(quad * 4 + r) * SATT + j * 16 + lm] = f2b(s[j][r]);
    __asm__ __volatile__("" ::: "memory");  // keep P reads below the stores

    #pragma unroll
    for (int ks = 0; ks < 2; ++ks) {
      bf16x8 ap = asbf(ld8(Pw + lm * SATT + ks * 32 + lk));
      #pragma unroll
      for (int j = 0; j < 4; j++) {
        int dg = 2 * j + (lm >> 3);
        int g  = (ks * 4 + quad) ^ (dg & 7);
        bf16x8 bv = asbf(ld8(&Vts[(j * 16 + lm) * 64 + g * 8]));
        oacc[j] = __builtin_amdgcn_mfma_f32_16x16x32_bf16(ap, bv, oacc[j], 0, 0, 0);
      }
    }
  }

  // epilogue: in-place write over own Q rows
  #pragma unroll
  for (int r = 0; r < 4; r++) {
    float inv = 1.0f / l_i[r];
    int row = qt * 64 + wave * 16 + quad * 4 + r;
    #pragma unroll
    for (int j = 0; j < 4; j++)
      Qh[(size_t)row * HD + j * 16 + lm] = f2b(oacc[j][r] * inv);
  }
}

// Output projection: d_out(f32) = ao @ Wo^T + bo ; ao in [N,16,L,64] bf16.
__global__ __launch_bounds__(256) void gemm_out(
    const u16* __restrict__ ao, const u16* __restrict__ Wo,
    const float* __restrict__ bo, float* __restrict__ out)
{
  __shared__ __align__(16) u16 As[128 * 32];
  __shared__ __align__(16) u16 Bs[128 * 32];
  const int m0 = blockIdx.y * 128, n0 = blockIdx.x * 128;
  f32x4 acc[4][4];
  gemm_acc_128x128<1>(ao, Wo, m0, n0, As, Bs, acc);

  const int lane = threadIdx.x & 63, wave = threadIdx.x >> 6;
  const int wm = (wave >> 1) * 64, wn = (wave & 1) * 64;
  const int lm = lane & 15, quad = lane >> 4;
  #pragma unroll
  for (int j = 0; j < 4; j++) {
    int col = n0 + wn + j * 16 + lm;
    float bias = bo[col];
    #pragma unroll
    for (int i = 0; i < 4; i++)
      #pragma unroll
      for (int r = 0; r < 4; r++) {
        int row = m0 + wm + i * 16 + quad * 4 + r;
        out[(size_t)row * EMB + col] = acc[i][j][r] + bias;
      }
  }
}

extern "C" void kernel_launch(void* const* d_in, const int* in_sizes, int n_in,
                              void* d_out, int out_size, void* d_ws, size_t ws_size,
                              hipStream_t stream)
{
  const float* xf  = (const float*)d_in[0];
  const float* Wqf = (const float*)d_in[2];
  const float* Wkf = (const float*)d_in[3];
  const float* Wvf = (const float*)d_in[4];
  const float* gq  = (const float*)d_in[5];
  const float* bq  = (const float*)d_in[6];
  const float* gk  = (const float*)d_in[7];
  const float* bk  = (const float*)d_in[8];
  const float* Wof = (const float*)d_in[9];
  const float* bo  = (const float*)d_in[10];

  const size_t MB = 1u << 20;
  u16* xb  = (u16*)d_ws;                           // 8 MiB
  u16* wqb = xb  + (size_t)ROWS * EMB;             // 2 MiB each
  u16* wkb = wqb + (size_t)EMB * EMB;
  u16* wvb = wkb + (size_t)EMB * EMB;
  u16* wob = wvb + (size_t)EMB * EMB;
  u16* kvbase = wob + (size_t)EMB * EMB;           // ws + 16 MiB

  size_t avail = (ws_size > 16 * MB) ? ws_size - 16 * MB : 2 * MB;
  int hpp = NHEAD;
  while ((size_t)hpp * MB > avail && hpp > 2) hpp >>= 1;
  const size_t kv_elems = (size_t)hpp * NBATCH * SEQ * HD;
  u16* kbuf = kvbase;
  u16* vbuf = kbuf + kv_elems;

  // Q (bf16, + in-place attn output) lives in the x input buffer (dead
  // after cvt_all; 8 MiB of its 16). gemm_out writes f32 straight to d_out.
  u16* qd = (u16*)d_in[0];
  float* out = (float*)d_out;

  cvt_all<<<dim3(8192), 256, 0, stream>>>(xf, Wqf, Wkf, Wvf, Wof,
                                          xb, wqb, wkb, wvb, wob);
  if (hpp == NHEAD) {
    gemm_qkv<<<dim3(8, 32, 3), 256, 0, stream>>>(xb, wqb, wkb, wvb,
                                                 gq, bq, gk, bk,
                                                 qd, kbuf, vbuf);
    attn<<<dim3(32, NHEAD, NBATCH), 256, 0, stream>>>(qd, kbuf, vbuf, 0, NHEAD);
  } else {
    gemm_q<<<dim3(8, 32), 256, 0, stream>>>(xb, wqb, gq, bq, qd);
    for (int g = 0; g < NHEAD / hpp; ++g) {
      gemm_kv<<<dim3(hpp / 2, 32, 2), 256, 0, stream>>>(xb, wkb, wvb, gk, bk,
                                                        kbuf, vbuf, g * hpp, hpp);
      attn<<<dim3(32, hpp, NBATCH), 256, 0, stream>>>(qd, kbuf, vbuf, g * hpp, hpp);
    }
  }
  gemm_out<<<dim3(8, 32), 256, 0, stream>>>(qd, wob, bo, out);
}

// Round 9
// 251.505 us; speedup vs baseline: 1.2409x; 1.2409x over previous
//
#include <hip/hip_runtime.h>
#include <stdint.h>

typedef unsigned short u16;
typedef u16   u16x4    __attribute__((ext_vector_type(4)));
typedef u16   u16x8    __attribute__((ext_vector_type(8)));
typedef u16x8 u16x8_ma __attribute__((may_alias));
typedef __bf16 bf16x8  __attribute__((ext_vector_type(8)));
typedef float f32x4    __attribute__((ext_vector_type(4)));
typedef f32x4 f32x4_ma __attribute__((may_alias));

#define EMB    1024
#define NHEAD  16
#define HD     64
#define SEQ    2048
#define NBATCH 2
#define ROWS   (NBATCH*SEQ)   // 4096
#define SATT   72             // attn K/P LDS row stride (r6-measured optimum)

__device__ __forceinline__ u16 f2b(float f) {
  uint32_t u; __builtin_memcpy(&u, &f, 4);
  u = u + 0x7fffu + ((u >> 16) & 1u);
  return (u16)(u >> 16);
}
__device__ __forceinline__ u16x8 ld8(const u16* p) { return *(const u16x8_ma*)p; }
__device__ __forceinline__ void  st8(u16* p, u16x8 v) { *(u16x8_ma*)p = v; }
__device__ __forceinline__ bf16x8 asbf(u16x8 v) {
  union { u16x8 u; bf16x8 b; } c; c.u = v; return c.b;
}
// async global->LDS, 16B/lane; LDS dest = wave-uniform base + lane*16 (m97).
__device__ __forceinline__ void async_cp16(const u16* g, u16* l) {
  __builtin_amdgcn_global_load_lds(
      (const __attribute__((address_space(1))) void*)g,
      (__attribute__((address_space(3))) void*)l, 16, 0, 0);
}

// ---------------------------------------------------------------------------
// Fused f32 -> bf16 conversion: x (4096 blocks) + 4 weights (1024 each).
// ---------------------------------------------------------------------------
__global__ __launch_bounds__(256) void cvt_all(
    const float* __restrict__ x,
    const float* __restrict__ w0, const float* __restrict__ w1,
    const float* __restrict__ w2, const float* __restrict__ w3,
    u16* __restrict__ xd, u16* __restrict__ d0, u16* __restrict__ d1,
    u16* __restrict__ d2, u16* __restrict__ d3)
{
  int bid = blockIdx.x;
  const float* s; u16* d; int off;
  if (bid < 4096) { s = x; d = xd; off = bid; }
  else {
    int t = bid - 4096; int m = t >> 10; off = t & 1023;
    switch (m) {
      case 0: s = w0; d = d0; break;
      case 1: s = w1; d = d1; break;
      case 2: s = w2; d = d2; break;
      default: s = w3; d = d3; break;
    }
  }
  size_t i = ((size_t)off * 256 + threadIdx.x) * 4;
  f32x4 v = *(const f32x4_ma*)(s + i);
  u16x4 o;
  #pragma unroll
  for (int j = 0; j < 4; j++) o[j] = f2b(v[j]);
  *(u16x4*)(d + i) = o;
}

// ---------------------------------------------------------------------------
// 128x128 GEMM core, m97 structure (global_load_lds width-16, stride-32 LDS).
// AMODE=0: A row-major. AMODE=1: A in [N,16,L,64]. B n-major.
// ---------------------------------------------------------------------------
template<int AMODE>
__device__ __forceinline__ void gemm_acc_128x128(
    const u16* __restrict__ A, const u16* __restrict__ B,
    int m0, int n0, u16* As, u16* Bs, f32x4 acc[4][4])
{
  const int tid  = threadIdx.x;
  const int lane = tid & 63;
  const int wave = tid >> 6;
  const int wm   = (wave >> 1) * 64;
  const int wn   = (wave & 1) * 64;
  const int ar   = tid >> 2;
  const int ac   = (tid & 3) * 8;
  const int lm   = lane & 15;
  const int lk   = (lane >> 4) * 8;

  #pragma unroll
  for (int i = 0; i < 4; i++)
    #pragma unroll
    for (int j = 0; j < 4; j++)
      #pragma unroll
      for (int e = 0; e < 4; e++) acc[i][j][e] = 0.f;

  for (int k0 = 0; k0 < EMB; k0 += 32) {
    size_t a0off, a1off;
    if (AMODE == 0) {
      a0off = (size_t)(m0 + ar)      * EMB + k0 + ac;
      a1off = (size_t)(m0 + ar + 64) * EMB + k0 + ac;
    } else {
      int col = k0 + ac, h = col >> 6, d = col & 63;
      int r0 = m0 + ar, r1 = m0 + ar + 64;
      a0off = (((size_t)((r0 >> 11) * NHEAD + h)) * SEQ + (r0 & (SEQ-1))) * HD + d;
      a1off = (((size_t)((r1 >> 11) * NHEAD + h)) * SEQ + (r1 & (SEQ-1))) * HD + d;
    }
    __syncthreads();
    async_cp16(A + a0off, As + tid * 8);
    async_cp16(A + a1off, As + (tid + 256) * 8);
    async_cp16(B + (size_t)(n0 + ar)      * EMB + k0 + ac, Bs + tid * 8);
    async_cp16(B + (size_t)(n0 + ar + 64) * EMB + k0 + ac, Bs + (tid + 256) * 8);
    __syncthreads();

    bf16x8 af[4], bfr[4];
    #pragma unroll
    for (int i = 0; i < 4; i++)
      af[i] = asbf(ld8(As + (wm + i * 16 + lm) * 32 + lk));
    #pragma unroll
    for (int j = 0; j < 4; j++)
      bfr[j] = asbf(ld8(Bs + (wn + j * 16 + lm) * 32 + lk));
    #pragma unroll
    for (int i = 0; i < 4; i++)
      #pragma unroll
      for (int j = 0; j < 4; j++)
        acc[i][j] = __builtin_amdgcn_mfma_f32_16x16x32_bf16(af[i], bfr[j], acc[i][j], 0, 0, 0);
  }
}

// LN over the wave's 64-col head span + scatter to bf16 [N, Hdst, L, 64].
__device__ __forceinline__ void epilogue_scatter_ln(
    f32x4 acc[4][4], u16* dst, int m0, int n0, int head_base, int Hdst,
    const float* g, const float* b, int do_ln)
{
  const int lane = threadIdx.x & 63, wave = threadIdx.x >> 6;
  const int wm = (wave >> 1) * 64, wn = (wave & 1) * 64;
  const int lm = lane & 15, quad = lane >> 4;

  float gv[4], bv[4];
  #pragma unroll
  for (int j = 0; j < 4; j++) { gv[j] = g[j * 16 + lm]; bv[j] = b[j * 16 + lm]; }

  #pragma unroll
  for (int i = 0; i < 4; i++)
    #pragma unroll
    for (int r = 0; r < 4; r++) {
      float val[4];
      #pragma unroll
      for (int j = 0; j < 4; j++) val[j] = acc[i][j][r];
      if (do_ln) {
        float s = val[0] + val[1] + val[2] + val[3];
        #pragma unroll
        for (int o = 8; o >= 1; o >>= 1) s += __shfl_xor(s, o, 64);
        float mean = s * (1.f / 64.f);
        float ss = 0.f;
        #pragma unroll
        for (int j = 0; j < 4; j++) { val[j] -= mean; ss += val[j] * val[j]; }
        #pragma unroll
        for (int o = 8; o >= 1; o >>= 1) ss += __shfl_xor(ss, o, 64);
        float inv = rsqrtf(ss * (1.f / 64.f) + 1e-5f);
        #pragma unroll
        for (int j = 0; j < 4; j++) val[j] = val[j] * inv * gv[j] + bv[j];
      }
      int row = m0 + wm + i * 16 + quad * 4 + r;
      int bn = row >> 11, l = row & (SEQ - 1);
      #pragma unroll
      for (int j = 0; j < 4; j++) {
        int col = n0 + wn + j * 16 + lm;
        int hl = (col >> 6) - head_base, d = col & 63;
        dst[(((size_t)(bn * Hdst + hl)) * SEQ + l) * HD + d] = f2b(val[j]);
      }
    }
}

// Merged QKV projection: grid (8, 32, 3).
__global__ __launch_bounds__(256) void gemm_qkv(
    const u16* __restrict__ x,
    const u16* __restrict__ Wq, const u16* __restrict__ Wk, const u16* __restrict__ Wv,
    const float* __restrict__ gq, const float* __restrict__ bq,
    const float* __restrict__ gk, const float* __restrict__ bk,
    u16* __restrict__ qd, u16* __restrict__ kb, u16* __restrict__ vb)
{
  __shared__ __align__(16) u16 As[128 * 32];
  __shared__ __align__(16) u16 Bs[128 * 32];
  const u16* W; u16* dst; const float* g; const float* b; int ln;
  if (blockIdx.z == 0)      { W = Wq; dst = qd; g = gq; b = bq; ln = 1; }
  else if (blockIdx.z == 1) { W = Wk; dst = kb; g = gk; b = bk; ln = 1; }
  else                      { W = Wv; dst = vb; g = gq; b = bq; ln = 0; }
  const int m0 = blockIdx.y * 128, n0 = blockIdx.x * 128;
  f32x4 acc[4][4];
  gemm_acc_128x128<0>(x, W, m0, n0, As, Bs, acc);
  epilogue_scatter_ln(acc, dst, m0, n0, 0, NHEAD, g, b, ln);
}

// Fallback kernels for small-workspace multi-pass K/V.
__global__ __launch_bounds__(256) void gemm_q(
    const u16* __restrict__ x, const u16* __restrict__ Wq,
    const float* __restrict__ gq, const float* __restrict__ bq,
    u16* __restrict__ qd)
{
  __shared__ __align__(16) u16 As[128 * 32];
  __shared__ __align__(16) u16 Bs[128 * 32];
  const int m0 = blockIdx.y * 128, n0 = blockIdx.x * 128;
  f32x4 acc[4][4];
  gemm_acc_128x128<0>(x, Wq, m0, n0, As, Bs, acc);
  epilogue_scatter_ln(acc, qd, m0, n0, 0, NHEAD, gq, bq, 1);
}
__global__ __launch_bounds__(256) void gemm_kv(
    const u16* __restrict__ x,
    const u16* __restrict__ Wk, const u16* __restrict__ Wv,
    const float* __restrict__ gk, const float* __restrict__ bk,
    u16* __restrict__ k, u16* __restrict__ v, int head_lo, int hpp)
{
  __shared__ __align__(16) u16 As[128 * 32];
  __shared__ __align__(16) u16 Bs[128 * 32];
  const int m0 = blockIdx.y * 128, n0 = blockIdx.x * 128;
  const u16* W = (blockIdx.z == 0 ? Wk : Wv) + (size_t)head_lo * HD * EMB;
  u16* dst = (blockIdx.z == 0) ? k : v;
  f32x4 acc[4][4];
  gemm_acc_128x128<0>(x, W, m0, n0, As, Bs, acc);
  epilogue_scatter_ln(acc, dst, m0, n0, 0, hpp, gk, bk, blockIdx.z == 0);
}

// ---------------------------------------------------------------------------
// Flash causal attention — r6-measured structure restored VERBATIM.
// Paired q-tiles qa=p / qb=31-p share one K/V stream; double-buffered LDS,
// ONE barrier per key-tile; Q fragments in registers; max-based softmax.
// grid (16, hpp, NBATCH), block 256.
// ---------------------------------------------------------------------------
__global__ __launch_bounds__(256) void attn(
    u16* qd, const u16* __restrict__ K, const u16* __restrict__ V,
    int head_lo, int hpp)
{
  __shared__ __align__(16) u16 Ks[2][64 * SATT];
  __shared__ __align__(16) u16 Vts[2][64 * 64];     // XOR-swizzled transpose
  __shared__ __align__(16) u16 Ps[4][16 * SATT];    // per-wave P strip

  const int p = blockIdx.x, hl = blockIdx.y, n = blockIdx.z;
  const int qa = p, qb = 31 - p;
  const int tid = threadIdx.x, lane = tid & 63, wave = tid >> 6;
  const int lm = lane & 15, quad = lane >> 4, lk = quad * 8;
  u16* Qh = qd + ((size_t)(n * NHEAD + head_lo + hl)) * SEQ * HD;
  const u16* Kh = K + ((size_t)(n * hpp + hl)) * SEQ * HD;
  const u16* Vh = V + ((size_t)(n * hpp + hl)) * SEQ * HD;

  const int sr = tid >> 3;        // 0..31 (key)
  const int sc = (tid & 7) * 8;   // 0..56 (d base)
  const int vswz = tid & 7;

  bf16x8 aqA[2], aqB[2];
  #pragma unroll
  for (int ks = 0; ks < 2; ++ks) {
    aqA[ks] = asbf(ld8(Qh + (size_t)(qa * 64 + wave * 16 + lm) * HD + ks * 32 + lk));
    aqB[ks] = asbf(ld8(Qh + (size_t)(qb * 64 + wave * 16 + lm) * HD + ks * 32 + lk));
  }

  u16x8 kr0, kr1, vr0, vr1;
  kr0 = ld8(Kh + (size_t)(sr)      * HD + sc);
  kr1 = ld8(Kh + (size_t)(sr + 32) * HD + sc);
  vr0 = ld8(Vh + (size_t)(sr)      * HD + sc);
  vr1 = ld8(Vh + (size_t)(sr + 32) * HD + sc);
  st8(&Ks[0][sr * SATT + sc], kr0);
  st8(&Ks[0][(sr + 32) * SATT + sc], kr1);
  #pragma unroll
  for (int jj = 0; jj < 8; jj++) {
    int d = sc + jj;
    Vts[0][d * 64 + (((sr >> 3) ^ vswz) * 8) + (sr & 7)]        = vr0[jj];
    Vts[0][d * 64 + ((((sr + 32) >> 3) ^ vswz) * 8) + (sr & 7)] = vr1[jj];
  }
  kr0 = ld8(Kh + (size_t)(64 + sr)      * HD + sc);
  kr1 = ld8(Kh + (size_t)(64 + sr + 32) * HD + sc);
  vr0 = ld8(Vh + (size_t)(64 + sr)      * HD + sc);
  vr1 = ld8(Vh + (size_t)(64 + sr + 32) * HD + sc);
  __syncthreads();

  f32x4 oA[4], oB[4];
  float mA[4], lA[4], mB[4], lB[4];
  #pragma unroll
  for (int j = 0; j < 4; j++)
    #pragma unroll
    for (int e = 0; e < 4; e++) { oA[j][e] = 0.f; oB[j][e] = 0.f; }
  #pragma unroll
  for (int r = 0; r < 4; r++) { mA[r] = -1e30f; lA[r] = 0.f; mB[r] = -1e30f; lB[r] = 0.f; }

  u16* Pw = &Ps[wave][0];

  for (int t = 0; t <= qb; ++t) {
    const int cur = t & 1;
    if (t < qb) {
      const int nb = 1 - cur;
      st8(&Ks[nb][sr * SATT + sc], kr0);
      st8(&Ks[nb][(sr + 32) * SATT + sc], kr1);
      #pragma unroll
      for (int jj = 0; jj < 8; jj++) {
        int d = sc + jj;
        Vts[nb][d * 64 + (((sr >> 3) ^ vswz) * 8) + (sr & 7)]        = vr0[jj];
        Vts[nb][d * 64 + ((((sr + 32) >> 3) ^ vswz) * 8) + (sr & 7)] = vr1[jj];
      }
      if (t + 1 < qb) {
        const size_t base = (size_t)(t + 2) * 64;
        kr0 = ld8(Kh + (base + sr)      * HD + sc);
        kr1 = ld8(Kh + (base + sr + 32) * HD + sc);
        vr0 = ld8(Vh + (base + sr)      * HD + sc);
        vr1 = ld8(Vh + (base + sr + 32) * HD + sc);
      }
    }

    #pragma unroll
    for (int tile = 0; tile < 2; ++tile) {
      if (tile == 1 && t > qa) break;
      const int qx = tile ? qa : qb;
      bf16x8* aq = tile ? aqA : aqB;
      f32x4*  oacc = tile ? oA : oB;
      float*  m_i = tile ? mA : mB;
      float*  l_i = tile ? lA : lB;

      f32x4 s[4];
      #pragma unroll
      for (int j = 0; j < 4; j++)
        #pragma unroll
        for (int e = 0; e < 4; e++) s[j][e] = 0.f;
      #pragma unroll
      for (int ks = 0; ks < 2; ++ks)
        #pragma unroll
        for (int j = 0; j < 4; j++) {
          bf16x8 bk = asbf(ld8(&Ks[cur][(j * 16 + lm) * SATT + ks * 32 + lk]));
          s[j] = __builtin_amdgcn_mfma_f32_16x16x32_bf16(aq[ks], bk, s[j], 0, 0, 0);
        }
      if (t == qx) {   // causal mask on the diagonal tile
        #pragma unroll
        for (int j = 0; j < 4; j++) {
          int col = t * 64 + j * 16 + lm;
          #pragma unroll
          for (int r = 0; r < 4; r++) {
            int row = qx * 64 + wave * 16 + quad * 4 + r;
            if (col > row) s[j][r] = -1e30f;
          }
        }
      }
      float mnew[4], alpha[4], rsum[4];
      #pragma unroll
      for (int r = 0; r < 4; r++) {
        float mx = fmaxf(fmaxf(s[0][r], s[1][r]), fmaxf(s[2][r], s[3][r]));
        #pragma unroll
        for (int o = 8; o >= 1; o >>= 1) mx = fmaxf(mx, __shfl_xor(mx, o, 64));
        mnew[r] = fmaxf(m_i[r], mx);
        alpha[r] = __expf(m_i[r] - mnew[r]);
        m_i[r] = mnew[r];
        rsum[r] = 0.f;
      }
      #pragma unroll
      for (int j = 0; j < 4; j++)
        #pragma unroll
        for (int r = 0; r < 4; r++) {
          float pv = __expf(s[j][r] - mnew[r]);
          s[j][r] = pv;
          rsum[r] += pv;
        }
      #pragma unroll
      for (int r = 0; r < 4; r++) {
        #pragma unroll
        for (int o = 8; o >= 1; o >>= 1) rsum[r] += __shfl_xor(rsum[r], o, 64);
        l_i[r] = l_i[r] * alpha[r] + rsum[r];
      }
      #pragma unroll
      for (int j = 0; j < 4; j++)
        #pragma unroll
        for (int r = 0; r < 4; r++) oacc[j][r] *= alpha[r];

      #pragma unroll
      for (int j = 0; j < 4; j++)
        #pragma unroll
        for (int r = 0; r < 4; r++)
          Pw[(quad * 4 + r) * SATT + j * 16 + lm] = f2b(s[j][r]);
      __asm__ __volatile__("" ::: "memory");

      #pragma unroll
      for (int ks = 0; ks < 2; ++ks) {
        bf16x8 ap = asbf(ld8(Pw + lm * SATT + ks * 32 + lk));
        #pragma unroll
        for (int j = 0; j < 4; j++) {
          int dg = 2 * j + (lm >> 3);
          int g  = (ks * 4 + quad) ^ (dg & 7);
          bf16x8 bv = asbf(ld8(&Vts[cur][(j * 16 + lm) * 64 + g * 8]));
          oacc[j] = __builtin_amdgcn_mfma_f32_16x16x32_bf16(ap, bv, oacc[j], 0, 0, 0);
        }
      }
    }
    __syncthreads();   // single per-iteration barrier (dbuf swap)
  }

  // epilogue: in-place write over own Q rows
  #pragma unroll
  for (int r = 0; r < 4; r++) {
    float invB = 1.0f / lB[r];
    float invA = 1.0f / lA[r];
    int rowB = qb * 64 + wave * 16 + quad * 4 + r;
    int rowA = qa * 64 + wave * 16 + quad * 4 + r;
    #pragma unroll
    for (int j = 0; j < 4; j++) {
      Qh[(size_t)rowB * HD + j * 16 + lm] = f2b(oB[j][r] * invB);
      Qh[(size_t)rowA * HD + j * 16 + lm] = f2b(oA[j][r] * invA);
    }
  }
}

// ---------------------------------------------------------------------------
// Output projection, 64x128 tiles for 2 blocks/CU occupancy: grid (8, 64).
// d_out(f32) = ao @ Wo^T + bo ; ao in [N,16,L,64] bf16.
// ---------------------------------------------------------------------------
__global__ __launch_bounds__(256) void gemm_out(
    const u16* __restrict__ ao, const u16* __restrict__ Wo,
    const float* __restrict__ bo, float* __restrict__ out)
{
  __shared__ __align__(16) u16 As[64 * 32];
  __shared__ __align__(16) u16 Bs[128 * 32];
  const int m0 = blockIdx.y * 64, n0 = blockIdx.x * 128;
  const int tid  = threadIdx.x;
  const int lane = tid & 63;
  const int wave = tid >> 6;
  const int wm   = (wave >> 1) * 32;
  const int wn   = (wave & 1) * 64;
  const int ar   = tid >> 2;
  const int ac   = (tid & 3) * 8;
  const int lm   = lane & 15;
  const int lk   = (lane >> 4) * 8;

  f32x4 acc[2][4];
  #pragma unroll
  for (int i = 0; i < 2; i++)
    #pragma unroll
    for (int j = 0; j < 4; j++)
      #pragma unroll
      for (int e = 0; e < 4; e++) acc[i][j][e] = 0.f;

  for (int k0 = 0; k0 < EMB; k0 += 32) {
    int col = k0 + ac, h = col >> 6, d = col & 63;
    int r0 = m0 + ar;
    size_t a0off = (((size_t)((r0 >> 11) * NHEAD + h)) * SEQ + (r0 & (SEQ-1))) * HD + d;
    __syncthreads();
    async_cp16(ao + a0off, As + tid * 8);
    async_cp16(Wo + (size_t)(n0 + ar)      * EMB + k0 + ac, Bs + tid * 8);
    async_cp16(Wo + (size_t)(n0 + ar + 64) * EMB + k0 + ac, Bs + (tid + 256) * 8);
    __syncthreads();

    bf16x8 af[2], bfr[4];
    #pragma unroll
    for (int i = 0; i < 2; i++)
      af[i] = asbf(ld8(As + (wm + i * 16 + lm) * 32 + lk));
    #pragma unroll
    for (int j = 0; j < 4; j++)
      bfr[j] = asbf(ld8(Bs + (wn + j * 16 + lm) * 32 + lk));
    #pragma unroll
    for (int i = 0; i < 2; i++)
      #pragma unroll
      for (int j = 0; j < 4; j++)
        acc[i][j] = __builtin_amdgcn_mfma_f32_16x16x32_bf16(af[i], bfr[j], acc[i][j], 0, 0, 0);
  }

  const int quad = lane >> 4;
  #pragma unroll
  for (int j = 0; j < 4; j++) {
    int col = n0 + wn + j * 16 + lm;
    float bias = bo[col];
    #pragma unroll
    for (int i = 0; i < 2; i++)
      #pragma unroll
      for (int r = 0; r < 4; r++) {
        int row = m0 + wm + i * 16 + quad * 4 + r;
        out[(size_t)row * EMB + col] = acc[i][j][r] + bias;
      }
  }
}

extern "C" void kernel_launch(void* const* d_in, const int* in_sizes, int n_in,
                              void* d_out, int out_size, void* d_ws, size_t ws_size,
                              hipStream_t stream)
{
  const float* xf  = (const float*)d_in[0];
  const float* Wqf = (const float*)d_in[2];
  const float* Wkf = (const float*)d_in[3];
  const float* Wvf = (const float*)d_in[4];
  const float* gq  = (const float*)d_in[5];
  const float* bq  = (const float*)d_in[6];
  const float* gk  = (const float*)d_in[7];
  const float* bk  = (const float*)d_in[8];
  const float* Wof = (const float*)d_in[9];
  const float* bo  = (const float*)d_in[10];

  const size_t MB = 1u << 20;
  u16* xb  = (u16*)d_ws;                           // 8 MiB
  u16* wqb = xb  + (size_t)ROWS * EMB;             // 2 MiB each
  u16* wkb = wqb + (size_t)EMB * EMB;
  u16* wvb = wkb + (size_t)EMB * EMB;
  u16* wob = wvb + (size_t)EMB * EMB;
  u16* kvbase = wob + (size_t)EMB * EMB;           // ws + 16 MiB

  size_t avail = (ws_size > 16 * MB) ? ws_size - 16 * MB : 2 * MB;
  int hpp = NHEAD;
  while ((size_t)hpp * MB > avail && hpp > 2) hpp >>= 1;
  const size_t kv_elems = (size_t)hpp * NBATCH * SEQ * HD;
  u16* kbuf = kvbase;
  u16* vbuf = kbuf + kv_elems;

  // Q (bf16, + in-place attn output) lives in the x input buffer (dead
  // after cvt_all). gemm_out writes f32 straight to d_out.
  u16* qd = (u16*)d_in[0];
  float* out = (float*)d_out;

  cvt_all<<<dim3(8192), 256, 0, stream>>>(xf, Wqf, Wkf, Wvf, Wof,
                                          xb, wqb, wkb, wvb, wob);
  if (hpp == NHEAD) {
    gemm_qkv<<<dim3(8, 32, 3), 256, 0, stream>>>(xb, wqb, wkb, wvb,
                                                 gq, bq, gk, bk,
                                                 qd, kbuf, vbuf);
    attn<<<dim3(16, NHEAD, NBATCH), 256, 0, stream>>>(qd, kbuf, vbuf, 0, NHEAD);
  } else {
    gemm_q<<<dim3(8, 32), 256, 0, stream>>>(xb, wqb, gq, bq, qd);
    for (int g = 0; g < NHEAD / hpp; ++g) {
      gemm_kv<<<dim3(hpp / 2, 32, 2), 256, 0, stream>>>(xb, wkb, wvb, gk, bk,
                                                        kbuf, vbuf, g * hpp, hpp);
      attn<<<dim3(16, hpp, NBATCH), 256, 0, stream>>>(qd, kbuf, vbuf, g * hpp, hpp);
    }
  }
  gemm_out<<<dim3(8, 64), 256, 0, stream>>>(qd, wob, bo, out);
}

// Round 10
// 239.562 us; speedup vs baseline: 1.3028x; 1.0499x over previous
//
#include <hip/hip_runtime.h>
#include <stdint.h>

typedef unsigned short u16;
typedef u16   u16x4    __attribute__((ext_vector_type(4)));
typedef u16   u16x8    __attribute__((ext_vector_type(8)));
typedef u16x8 u16x8_ma __attribute__((may_alias));
typedef __bf16 bf16x8  __attribute__((ext_vector_type(8)));
typedef float f32x4    __attribute__((ext_vector_type(4)));
typedef f32x4 f32x4_ma __attribute__((may_alias));

#define EMB    1024
#define NHEAD  16
#define HD     64
#define SEQ    2048
#define NBATCH 2
#define ROWS   (NBATCH*SEQ)   // 4096
#define SATT   72             // attn K/P LDS row stride (r6-measured optimum)

__device__ __forceinline__ u16 f2b(float f) {
  uint32_t u; __builtin_memcpy(&u, &f, 4);
  u = u + 0x7fffu + ((u >> 16) & 1u);
  return (u16)(u >> 16);
}
__device__ __forceinline__ u16x8 ld8(const u16* p) { return *(const u16x8_ma*)p; }
__device__ __forceinline__ void  st8(u16* p, u16x8 v) { *(u16x8_ma*)p = v; }
__device__ __forceinline__ bf16x8 asbf(u16x8 v) {
  union { u16x8 u; bf16x8 b; } c; c.u = v; return c.b;
}
// async global->LDS, 16B/lane; LDS dest = wave-uniform base + lane*16 (m97).
__device__ __forceinline__ void async_cp16(const u16* g, u16* l) {
  __builtin_amdgcn_global_load_lds(
      (const __attribute__((address_space(1))) void*)g,
      (__attribute__((address_space(3))) void*)l, 16, 0, 0);
}

// ---------------------------------------------------------------------------
// Fused f32 -> bf16 conversion: x (4096 blocks) + 4 weights (1024 each).
// ---------------------------------------------------------------------------
__global__ __launch_bounds__(256) void cvt_all(
    const float* __restrict__ x,
    const float* __restrict__ w0, const float* __restrict__ w1,
    const float* __restrict__ w2, const float* __restrict__ w3,
    u16* __restrict__ xd, u16* __restrict__ d0, u16* __restrict__ d1,
    u16* __restrict__ d2, u16* __restrict__ d3)
{
  int bid = blockIdx.x;
  const float* s; u16* d; int off;
  if (bid < 4096) { s = x; d = xd; off = bid; }
  else {
    int t = bid - 4096; int m = t >> 10; off = t & 1023;
    switch (m) {
      case 0: s = w0; d = d0; break;
      case 1: s = w1; d = d1; break;
      case 2: s = w2; d = d2; break;
      default: s = w3; d = d3; break;
    }
  }
  size_t i = ((size_t)off * 256 + threadIdx.x) * 4;
  f32x4 v = *(const f32x4_ma*)(s + i);
  u16x4 o;
  #pragma unroll
  for (int j = 0; j < 4; j++) o[j] = f2b(v[j]);
  *(u16x4*)(d + i) = o;
}

// ---------------------------------------------------------------------------
// 128x128 GEMM core, m97 structure (global_load_lds width-16, stride-32 LDS).
// AMODE=0: A row-major. AMODE=1: A in [N,16,L,64]. B n-major.
// ---------------------------------------------------------------------------
template<int AMODE>
__device__ __forceinline__ void gemm_acc_128x128(
    const u16* __restrict__ A, const u16* __restrict__ B,
    int m0, int n0, u16* As, u16* Bs, f32x4 acc[4][4])
{
  const int tid  = threadIdx.x;
  const int lane = tid & 63;
  const int wave = tid >> 6;
  const int wm   = (wave >> 1) * 64;
  const int wn   = (wave & 1) * 64;
  const int ar   = tid >> 2;
  const int ac   = (tid & 3) * 8;
  const int lm   = lane & 15;
  const int lk   = (lane >> 4) * 8;

  #pragma unroll
  for (int i = 0; i < 4; i++)
    #pragma unroll
    for (int j = 0; j < 4; j++)
      #pragma unroll
      for (int e = 0; e < 4; e++) acc[i][j][e] = 0.f;

  for (int k0 = 0; k0 < EMB; k0 += 32) {
    size_t a0off, a1off;
    if (AMODE == 0) {
      a0off = (size_t)(m0 + ar)      * EMB + k0 + ac;
      a1off = (size_t)(m0 + ar + 64) * EMB + k0 + ac;
    } else {
      int col = k0 + ac, h = col >> 6, d = col & 63;
      int r0 = m0 + ar, r1 = m0 + ar + 64;
      a0off = (((size_t)((r0 >> 11) * NHEAD + h)) * SEQ + (r0 & (SEQ-1))) * HD + d;
      a1off = (((size_t)((r1 >> 11) * NHEAD + h)) * SEQ + (r1 & (SEQ-1))) * HD + d;
    }
    __syncthreads();
    async_cp16(A + a0off, As + tid * 8);
    async_cp16(A + a1off, As + (tid + 256) * 8);
    async_cp16(B + (size_t)(n0 + ar)      * EMB + k0 + ac, Bs + tid * 8);
    async_cp16(B + (size_t)(n0 + ar + 64) * EMB + k0 + ac, Bs + (tid + 256) * 8);
    __syncthreads();

    bf16x8 af[4], bfr[4];
    #pragma unroll
    for (int i = 0; i < 4; i++)
      af[i] = asbf(ld8(As + (wm + i * 16 + lm) * 32 + lk));
    #pragma unroll
    for (int j = 0; j < 4; j++)
      bfr[j] = asbf(ld8(Bs + (wn + j * 16 + lm) * 32 + lk));
    #pragma unroll
    for (int i = 0; i < 4; i++)
      #pragma unroll
      for (int j = 0; j < 4; j++)
        acc[i][j] = __builtin_amdgcn_mfma_f32_16x16x32_bf16(af[i], bfr[j], acc[i][j], 0, 0, 0);
  }
}

// LN over the wave's 64-col head span + scatter to bf16 [N, Hdst, L, 64].
__device__ __forceinline__ void epilogue_scatter_ln(
    f32x4 acc[4][4], u16* dst, int m0, int n0, int head_base, int Hdst,
    const float* g, const float* b, int do_ln)
{
  const int lane = threadIdx.x & 63, wave = threadIdx.x >> 6;
  const int wm = (wave >> 1) * 64, wn = (wave & 1) * 64;
  const int lm = lane & 15, quad = lane >> 4;

  float gv[4], bv[4];
  #pragma unroll
  for (int j = 0; j < 4; j++) { gv[j] = g[j * 16 + lm]; bv[j] = b[j * 16 + lm]; }

  #pragma unroll
  for (int i = 0; i < 4; i++)
    #pragma unroll
    for (int r = 0; r < 4; r++) {
      float val[4];
      #pragma unroll
      for (int j = 0; j < 4; j++) val[j] = acc[i][j][r];
      if (do_ln) {
        float s = val[0] + val[1] + val[2] + val[3];
        #pragma unroll
        for (int o = 8; o >= 1; o >>= 1) s += __shfl_xor(s, o, 64);
        float mean = s * (1.f / 64.f);
        float ss = 0.f;
        #pragma unroll
        for (int j = 0; j < 4; j++) { val[j] -= mean; ss += val[j] * val[j]; }
        #pragma unroll
        for (int o = 8; o >= 1; o >>= 1) ss += __shfl_xor(ss, o, 64);
        float inv = rsqrtf(ss * (1.f / 64.f) + 1e-5f);
        #pragma unroll
        for (int j = 0; j < 4; j++) val[j] = val[j] * inv * gv[j] + bv[j];
      }
      int row = m0 + wm + i * 16 + quad * 4 + r;
      int bn = row >> 11, l = row & (SEQ - 1);
      #pragma unroll
      for (int j = 0; j < 4; j++) {
        int col = n0 + wn + j * 16 + lm;
        int hl = (col >> 6) - head_base, d = col & 63;
        dst[(((size_t)(bn * Hdst + hl)) * SEQ + l) * HD + d] = f2b(val[j]);
      }
    }
}

// Merged QKV projection: grid (8, 32, 3).
__global__ __launch_bounds__(256) void gemm_qkv(
    const u16* __restrict__ x,
    const u16* __restrict__ Wq, const u16* __restrict__ Wk, const u16* __restrict__ Wv,
    const float* __restrict__ gq, const float* __restrict__ bq,
    const float* __restrict__ gk, const float* __restrict__ bk,
    u16* __restrict__ qd, u16* __restrict__ kb, u16* __restrict__ vb)
{
  __shared__ __align__(16) u16 As[128 * 32];
  __shared__ __align__(16) u16 Bs[128 * 32];
  const u16* W; u16* dst; const float* g; const float* b; int ln;
  if (blockIdx.z == 0)      { W = Wq; dst = qd; g = gq; b = bq; ln = 1; }
  else if (blockIdx.z == 1) { W = Wk; dst = kb; g = gk; b = bk; ln = 1; }
  else                      { W = Wv; dst = vb; g = gq; b = bq; ln = 0; }
  const int m0 = blockIdx.y * 128, n0 = blockIdx.x * 128;
  f32x4 acc[4][4];
  gemm_acc_128x128<0>(x, W, m0, n0, As, Bs, acc);
  epilogue_scatter_ln(acc, dst, m0, n0, 0, NHEAD, g, b, ln);
}

// Fallback kernels for small-workspace multi-pass K/V.
__global__ __launch_bounds__(256) void gemm_q(
    const u16* __restrict__ x, const u16* __restrict__ Wq,
    const float* __restrict__ gq, const float* __restrict__ bq,
    u16* __restrict__ qd)
{
  __shared__ __align__(16) u16 As[128 * 32];
  __shared__ __align__(16) u16 Bs[128 * 32];
  const int m0 = blockIdx.y * 128, n0 = blockIdx.x * 128;
  f32x4 acc[4][4];
  gemm_acc_128x128<0>(x, Wq, m0, n0, As, Bs, acc);
  epilogue_scatter_ln(acc, qd, m0, n0, 0, NHEAD, gq, bq, 1);
}
__global__ __launch_bounds__(256) void gemm_kv(
    const u16* __restrict__ x,
    const u16* __restrict__ Wk, const u16* __restrict__ Wv,
    const float* __restrict__ gk, const float* __restrict__ bk,
    u16* __restrict__ k, u16* __restrict__ v, int head_lo, int hpp)
{
  __shared__ __align__(16) u16 As[128 * 32];
  __shared__ __align__(16) u16 Bs[128 * 32];
  const int m0 = blockIdx.y * 128, n0 = blockIdx.x * 128;
  const u16* W = (blockIdx.z == 0 ? Wk : Wv) + (size_t)head_lo * HD * EMB;
  u16* dst = (blockIdx.z == 0) ? k : v;
  f32x4 acc[4][4];
  gemm_acc_128x128<0>(x, W, m0, n0, As, Bs, acc);
  epilogue_scatter_ln(acc, dst, m0, n0, 0, hpp, gk, bk, blockIdx.z == 0);
}

// ---------------------------------------------------------------------------
// Flash causal attention — r6/r9 structure, ONE change: the per-tile rsum
// shuffle-reduction is replaced by per-lane partial sums rescaled by alpha
// (alpha is row-uniform since the max IS still reduced), with a single
// shuffle-reduce in the epilogue. Algebraically identical l_i.
// grid (16, hpp, NBATCH), block 256.
// ---------------------------------------------------------------------------
__global__ __launch_bounds__(256) void attn(
    u16* qd, const u16* __restrict__ K, const u16* __restrict__ V,
    int head_lo, int hpp)
{
  __shared__ __align__(16) u16 Ks[2][64 * SATT];
  __shared__ __align__(16) u16 Vts[2][64 * 64];     // XOR-swizzled transpose
  __shared__ __align__(16) u16 Ps[4][16 * SATT];    // per-wave P strip

  const int p = blockIdx.x, hl = blockIdx.y, n = blockIdx.z;
  const int qa = p, qb = 31 - p;
  const int tid = threadIdx.x, lane = tid & 63, wave = tid >> 6;
  const int lm = lane & 15, quad = lane >> 4, lk = quad * 8;
  u16* Qh = qd + ((size_t)(n * NHEAD + head_lo + hl)) * SEQ * HD;
  const u16* Kh = K + ((size_t)(n * hpp + hl)) * SEQ * HD;
  const u16* Vh = V + ((size_t)(n * hpp + hl)) * SEQ * HD;

  const int sr = tid >> 3;        // 0..31 (key)
  const int sc = (tid & 7) * 8;   // 0..56 (d base)
  const int vswz = tid & 7;

  bf16x8 aqA[2], aqB[2];
  #pragma unroll
  for (int ks = 0; ks < 2; ++ks) {
    aqA[ks] = asbf(ld8(Qh + (size_t)(qa * 64 + wave * 16 + lm) * HD + ks * 32 + lk));
    aqB[ks] = asbf(ld8(Qh + (size_t)(qb * 64 + wave * 16 + lm) * HD + ks * 32 + lk));
  }

  u16x8 kr0, kr1, vr0, vr1;
  kr0 = ld8(Kh + (size_t)(sr)      * HD + sc);
  kr1 = ld8(Kh + (size_t)(sr + 32) * HD + sc);
  vr0 = ld8(Vh + (size_t)(sr)      * HD + sc);
  vr1 = ld8(Vh + (size_t)(sr + 32) * HD + sc);
  st8(&Ks[0][sr * SATT + sc], kr0);
  st8(&Ks[0][(sr + 32) * SATT + sc], kr1);
  #pragma unroll
  for (int jj = 0; jj < 8; jj++) {
    int d = sc + jj;
    Vts[0][d * 64 + (((sr >> 3) ^ vswz) * 8) + (sr & 7)]        = vr0[jj];
    Vts[0][d * 64 + ((((sr + 32) >> 3) ^ vswz) * 8) + (sr & 7)] = vr1[jj];
  }
  kr0 = ld8(Kh + (size_t)(64 + sr)      * HD + sc);
  kr1 = ld8(Kh + (size_t)(64 + sr + 32) * HD + sc);
  vr0 = ld8(Vh + (size_t)(64 + sr)      * HD + sc);
  vr1 = ld8(Vh + (size_t)(64 + sr + 32) * HD + sc);
  __syncthreads();

  f32x4 oA[4], oB[4];
  float mA[4], psA[4], mB[4], psB[4];
  #pragma unroll
  for (int j = 0; j < 4; j++)
    #pragma unroll
    for (int e = 0; e < 4; e++) { oA[j][e] = 0.f; oB[j][e] = 0.f; }
  #pragma unroll
  for (int r = 0; r < 4; r++) { mA[r] = -1e30f; psA[r] = 0.f; mB[r] = -1e30f; psB[r] = 0.f; }

  u16* Pw = &Ps[wave][0];

  for (int t = 0; t <= qb; ++t) {
    const int cur = t & 1;
    if (t < qb) {
      const int nb = 1 - cur;
      st8(&Ks[nb][sr * SATT + sc], kr0);
      st8(&Ks[nb][(sr + 32) * SATT + sc], kr1);
      #pragma unroll
      for (int jj = 0; jj < 8; jj++) {
        int d = sc + jj;
        Vts[nb][d * 64 + (((sr >> 3) ^ vswz) * 8) + (sr & 7)]        = vr0[jj];
        Vts[nb][d * 64 + ((((sr + 32) >> 3) ^ vswz) * 8) + (sr & 7)] = vr1[jj];
      }
      if (t + 1 < qb) {
        const size_t base = (size_t)(t + 2) * 64;
        kr0 = ld8(Kh + (base + sr)      * HD + sc);
        kr1 = ld8(Kh + (base + sr + 32) * HD + sc);
        vr0 = ld8(Vh + (base + sr)      * HD + sc);
        vr1 = ld8(Vh + (base + sr + 32) * HD + sc);
      }
    }

    #pragma unroll
    for (int tile = 0; tile < 2; ++tile) {
      if (tile == 1 && t > qa) break;
      const int qx = tile ? qa : qb;
      bf16x8* aq = tile ? aqA : aqB;
      f32x4*  oacc = tile ? oA : oB;
      float*  m_i = tile ? mA : mB;
      float*  psum = tile ? psA : psB;

      f32x4 s[4];
      #pragma unroll
      for (int j = 0; j < 4; j++)
        #pragma unroll
        for (int e = 0; e < 4; e++) s[j][e] = 0.f;
      #pragma unroll
      for (int ks = 0; ks < 2; ++ks)
        #pragma unroll
        for (int j = 0; j < 4; j++) {
          bf16x8 bk = asbf(ld8(&Ks[cur][(j * 16 + lm) * SATT + ks * 32 + lk]));
          s[j] = __builtin_amdgcn_mfma_f32_16x16x32_bf16(aq[ks], bk, s[j], 0, 0, 0);
        }
      if (t == qx) {   // causal mask on the diagonal tile
        #pragma unroll
        for (int j = 0; j < 4; j++) {
          int col = t * 64 + j * 16 + lm;
          #pragma unroll
          for (int r = 0; r < 4; r++) {
            int row = qx * 64 + wave * 16 + quad * 4 + r;
            if (col > row) s[j][r] = -1e30f;
          }
        }
      }
      // row max (reduced -> alpha row-uniform); per-lane partial sums only.
      float mnew[4], alpha[4], part[4];
      #pragma unroll
      for (int r = 0; r < 4; r++) {
        float mx = fmaxf(fmaxf(s[0][r], s[1][r]), fmaxf(s[2][r], s[3][r]));
        #pragma unroll
        for (int o = 8; o >= 1; o >>= 1) mx = fmaxf(mx, __shfl_xor(mx, o, 64));
        mnew[r] = fmaxf(m_i[r], mx);
        alpha[r] = __expf(m_i[r] - mnew[r]);
        m_i[r] = mnew[r];
        part[r] = 0.f;
      }
      #pragma unroll
      for (int j = 0; j < 4; j++)
        #pragma unroll
        for (int r = 0; r < 4; r++) {
          float pv = __expf(s[j][r] - mnew[r]);
          s[j][r] = pv;
          part[r] += pv;
        }
      #pragma unroll
      for (int r = 0; r < 4; r++) psum[r] = psum[r] * alpha[r] + part[r];
      #pragma unroll
      for (int j = 0; j < 4; j++)
        #pragma unroll
        for (int r = 0; r < 4; r++) oacc[j][r] *= alpha[r];

      #pragma unroll
      for (int j = 0; j < 4; j++)
        #pragma unroll
        for (int r = 0; r < 4; r++)
          Pw[(quad * 4 + r) * SATT + j * 16 + lm] = f2b(s[j][r]);
      __asm__ __volatile__("" ::: "memory");

      #pragma unroll
      for (int ks = 0; ks < 2; ++ks) {
        bf16x8 ap = asbf(ld8(Pw + lm * SATT + ks * 32 + lk));
        #pragma unroll
        for (int j = 0; j < 4; j++) {
          int dg = 2 * j + (lm >> 3);
          int g  = (ks * 4 + quad) ^ (dg & 7);
          bf16x8 bv = asbf(ld8(&Vts[cur][(j * 16 + lm) * 64 + g * 8]));
          oacc[j] = __builtin_amdgcn_mfma_f32_16x16x32_bf16(ap, bv, oacc[j], 0, 0, 0);
        }
      }
    }
    __syncthreads();   // single per-iteration barrier (dbuf swap)
  }

  // epilogue: reduce the per-lane partial sums (16 lanes per row), write O
  #pragma unroll
  for (int r = 0; r < 4; r++) {
    float sA = psA[r], sB = psB[r];
    #pragma unroll
    for (int o = 8; o >= 1; o >>= 1) { sA += __shfl_xor(sA, o, 64); sB += __shfl_xor(sB, o, 64); }
    float invA = 1.0f / sA, invB = 1.0f / sB;
    int rowA = qa * 64 + wave * 16 + quad * 4 + r;
    int rowB = qb * 64 + wave * 16 + quad * 4 + r;
    #pragma unroll
    for (int j = 0; j < 4; j++) {
      Qh[(size_t)rowB * HD + j * 16 + lm] = f2b(oB[j][r] * invB);
      Qh[(size_t)rowA * HD + j * 16 + lm] = f2b(oA[j][r] * invA);
    }
  }
}

// ---------------------------------------------------------------------------
// Output projection, 64x128 tiles (2 blocks/CU): grid (8, 64).
// d_out(f32) = ao @ Wo^T + bo ; ao in [N,16,L,64] bf16.
// ---------------------------------------------------------------------------
__global__ __launch_bounds__(256) void gemm_out(
    const u16* __restrict__ ao, const u16* __restrict__ Wo,
    const float* __restrict__ bo, float* __restrict__ out)
{
  __shared__ __align__(16) u16 As[64 * 32];
  __shared__ __align__(16) u16 Bs[128 * 32];
  const int m0 = blockIdx.y * 64, n0 = blockIdx.x * 128;
  const int tid  = threadIdx.x;
  const int lane = tid & 63;
  const int wave = tid >> 6;
  const int wm   = (wave >> 1) * 32;
  const int wn   = (wave & 1) * 64;
  const int ar   = tid >> 2;
  const int ac   = (tid & 3) * 8;
  const int lm   = lane & 15;
  const int lk   = (lane >> 4) * 8;

  f32x4 acc[2][4];
  #pragma unroll
  for (int i = 0; i < 2; i++)
    #pragma unroll
    for (int j = 0; j < 4; j++)
      #pragma unroll
      for (int e = 0; e < 4; e++) acc[i][j][e] = 0.f;

  for (int k0 = 0; k0 < EMB; k0 += 32) {
    int col = k0 + ac, h = col >> 6, d = col & 63;
    int r0 = m0 + ar;
    size_t a0off = (((size_t)((r0 >> 11) * NHEAD + h)) * SEQ + (r0 & (SEQ-1))) * HD + d;
    __syncthreads();
    async_cp16(ao + a0off, As + tid * 8);
    async_cp16(Wo + (size_t)(n0 + ar)      * EMB + k0 + ac, Bs + tid * 8);
    async_cp16(Wo + (size_t)(n0 + ar + 64) * EMB + k0 + ac, Bs + (tid + 256) * 8);
    __syncthreads();

    bf16x8 af[2], bfr[4];
    #pragma unroll
    for (int i = 0; i < 2; i++)
      af[i] = asbf(ld8(As + (wm + i * 16 + lm) * 32 + lk));
    #pragma unroll
    for (int j = 0; j < 4; j++)
      bfr[j] = asbf(ld8(Bs + (wn + j * 16 + lm) * 32 + lk));
    #pragma unroll
    for (int i = 0; i < 2; i++)
      #pragma unroll
      for (int j = 0; j < 4; j++)
        acc[i][j] = __builtin_amdgcn_mfma_f32_16x16x32_bf16(af[i], bfr[j], acc[i][j], 0, 0, 0);
  }

  const int quad = lane >> 4;
  #pragma unroll
  for (int j = 0; j < 4; j++) {
    int col = n0 + wn + j * 16 + lm;
    float bias = bo[col];
    #pragma unroll
    for (int i = 0; i < 2; i++)
      #pragma unroll
      for (int r = 0; r < 4; r++) {
        int row = m0 + wm + i * 16 + quad * 4 + r;
        out[(size_t)row * EMB + col] = acc[i][j][r] + bias;
      }
  }
}

extern "C" void kernel_launch(void* const* d_in, const int* in_sizes, int n_in,
                              void* d_out, int out_size, void* d_ws, size_t ws_size,
                              hipStream_t stream)
{
  const float* xf  = (const float*)d_in[0];
  const float* Wqf = (const float*)d_in[2];
  const float* Wkf = (const float*)d_in[3];
  const float* Wvf = (const float*)d_in[4];
  const float* gq  = (const float*)d_in[5];
  const float* bq  = (const float*)d_in[6];
  const float* gk  = (const float*)d_in[7];
  const float* bk  = (const float*)d_in[8];
  const float* Wof = (const float*)d_in[9];
  const float* bo  = (const float*)d_in[10];

  const size_t MB = 1u << 20;
  u16* xb  = (u16*)d_ws;                           // 8 MiB
  u16* wqb = xb  + (size_t)ROWS * EMB;             // 2 MiB each
  u16* wkb = wqb + (size_t)EMB * EMB;
  u16* wvb = wkb + (size_t)EMB * EMB;
  u16* wob = wvb + (size_t)EMB * EMB;
  u16* kvbase = wob + (size_t)EMB * EMB;           // ws + 16 MiB

  size_t avail = (ws_size > 16 * MB) ? ws_size - 16 * MB : 2 * MB;
  int hpp = NHEAD;
  while ((size_t)hpp * MB > avail && hpp > 2) hpp >>= 1;
  const size_t kv_elems = (size_t)hpp * NBATCH * SEQ * HD;
  u16* kbuf = kvbase;
  u16* vbuf = kbuf + kv_elems;

  // Q (bf16, + in-place attn output) lives in the x input buffer (dead
  // after cvt_all). gemm_out writes f32 straight to d_out.
  u16* qd = (u16*)d_in[0];
  float* out = (float*)d_out;

  cvt_all<<<dim3(8192), 256, 0, stream>>>(xf, Wqf, Wkf, Wvf, Wof,
                                          xb, wqb, wkb, wvb, wob);
  if (hpp == NHEAD) {
    gemm_qkv<<<dim3(8, 32, 3), 256, 0, stream>>>(xb, wqb, wkb, wvb,
                                                 gq, bq, gk, bk,
                                                 qd, kbuf, vbuf);
    attn<<<dim3(16, NHEAD, NBATCH), 256, 0, stream>>>(qd, kbuf, vbuf, 0, NHEAD);
  } else {
    gemm_q<<<dim3(8, 32), 256, 0, stream>>>(xb, wqb, gq, bq, qd);
    for (int g = 0; g < NHEAD / hpp; ++g) {
      gemm_kv<<<dim3(hpp / 2, 32, 2), 256, 0, stream>>>(xb, wkb, wvb, gk, bk,
                                                        kbuf, vbuf, g * hpp, hpp);
      attn<<<dim3(16, hpp, NBATCH), 256, 0, stream>>>(qd, kbuf, vbuf, g * hpp, hpp);
    }
  }
  gemm_out<<<dim3(8, 64), 256, 0, stream>>>(qd, wob, bo, out);
}

// Round 11
// 229.879 us; speedup vs baseline: 1.3576x; 1.0421x over previous
//
#include <hip/hip_runtime.h>
#include <stdint.h>

typedef unsigned short u16;
typedef u16   u16x4    __attribute__((ext_vector_type(4)));
typedef u16   u16x8    __attribute__((ext_vector_type(8)));
typedef u16x8 u16x8_ma __attribute__((may_alias));
typedef __bf16 bf16x8  __attribute__((ext_vector_type(8)));
typedef float f32x4    __attribute__((ext_vector_type(4)));
typedef f32x4 f32x4_ma __attribute__((may_alias));

#define EMB    1024
#define NHEAD  16
#define HD     64
#define SEQ    2048
#define NBATCH 2
#define ROWS   (NBATCH*SEQ)   // 4096
#define SATT   72             // attn K/P LDS row stride (r6-measured optimum)

__device__ __forceinline__ u16 f2b(float f) {
  uint32_t u; __builtin_memcpy(&u, &f, 4);
  u = u + 0x7fffu + ((u >> 16) & 1u);
  return (u16)(u >> 16);
}
__device__ __forceinline__ u16x8 ld8(const u16* p) { return *(const u16x8_ma*)p; }
__device__ __forceinline__ void  st8(u16* p, u16x8 v) { *(u16x8_ma*)p = v; }
__device__ __forceinline__ bf16x8 asbf(u16x8 v) {
  union { u16x8 u; bf16x8 b; } c; c.u = v; return c.b;
}
// async global->LDS, 16B/lane; LDS dest = wave-uniform base + lane*16 (m97).
__device__ __forceinline__ void async_cp16(const u16* g, u16* l) {
  __builtin_amdgcn_global_load_lds(
      (const __attribute__((address_space(1))) void*)g,
      (__attribute__((address_space(3))) void*)l, 16, 0, 0);
}

// ---------------------------------------------------------------------------
// Fused f32 -> bf16 conversion: x (4096 blocks) + 4 weights (1024 each).
// ---------------------------------------------------------------------------
__global__ __launch_bounds__(256) void cvt_all(
    const float* __restrict__ x,
    const float* __restrict__ w0, const float* __restrict__ w1,
    const float* __restrict__ w2, const float* __restrict__ w3,
    u16* __restrict__ xd, u16* __restrict__ d0, u16* __restrict__ d1,
    u16* __restrict__ d2, u16* __restrict__ d3)
{
  int bid = blockIdx.x;
  const float* s; u16* d; int off;
  if (bid < 4096) { s = x; d = xd; off = bid; }
  else {
    int t = bid - 4096; int m = t >> 10; off = t & 1023;
    switch (m) {
      case 0: s = w0; d = d0; break;
      case 1: s = w1; d = d1; break;
      case 2: s = w2; d = d2; break;
      default: s = w3; d = d3; break;
    }
  }
  size_t i = ((size_t)off * 256 + threadIdx.x) * 4;
  f32x4 v = *(const f32x4_ma*)(s + i);
  u16x4 o;
  #pragma unroll
  for (int j = 0; j < 4; j++) o[j] = f2b(v[j]);
  *(u16x4*)(d + i) = o;
}

// ---------------------------------------------------------------------------
// 128x128 GEMM core, BK=64 via dual 128x32 panels (each panel is the exact
// m97 layout, so the async_cp16 wave-uniform constraint and the measured
// bank behavior are preserved). 8 async + 32 MFMA per barrier pair, 16 iters.
// AMODE=0: A row-major. AMODE=1: A in [N,16,L,64]. B n-major.
// ---------------------------------------------------------------------------
template<int AMODE>
__device__ __forceinline__ void gemm_acc_128x128(
    const u16* __restrict__ A, const u16* __restrict__ B,
    int m0, int n0, u16* As, u16* Bs, f32x4 acc[4][4])
{
  const int tid  = threadIdx.x;
  const int lane = tid & 63;
  const int wave = tid >> 6;
  const int wm   = (wave >> 1) * 64;
  const int wn   = (wave & 1) * 64;
  const int ar   = tid >> 2;        // 0..63
  const int ac   = (tid & 3) * 8;   // 0,8,16,24
  const int lm   = lane & 15;
  const int lk   = (lane >> 4) * 8;

  #pragma unroll
  for (int i = 0; i < 4; i++)
    #pragma unroll
    for (int j = 0; j < 4; j++)
      #pragma unroll
      for (int e = 0; e < 4; e++) acc[i][j][e] = 0.f;

  for (int k0 = 0; k0 < EMB; k0 += 64) {
    size_t a0[2], a1[2];
    #pragma unroll
    for (int pnl = 0; pnl < 2; pnl++) {
      int kc = k0 + pnl * 32 + ac;
      if (AMODE == 0) {
        a0[pnl] = (size_t)(m0 + ar)      * EMB + kc;
        a1[pnl] = (size_t)(m0 + ar + 64) * EMB + kc;
      } else {
        int h = kc >> 6, d = kc & 63;
        int r0 = m0 + ar, r1 = m0 + ar + 64;
        a0[pnl] = (((size_t)((r0 >> 11) * NHEAD + h)) * SEQ + (r0 & (SEQ-1))) * HD + d;
        a1[pnl] = (((size_t)((r1 >> 11) * NHEAD + h)) * SEQ + (r1 & (SEQ-1))) * HD + d;
      }
    }
    __syncthreads();   // previous iteration's LDS reads complete
    #pragma unroll
    for (int pnl = 0; pnl < 2; pnl++) {
      const int pb = pnl * 4096;   // panel base (elems)
      async_cp16(A + a0[pnl], As + pb + tid * 8);
      async_cp16(A + a1[pnl], As + pb + (tid + 256) * 8);
      async_cp16(B + (size_t)(n0 + ar)      * EMB + k0 + pnl * 32 + ac, Bs + pb + tid * 8);
      async_cp16(B + (size_t)(n0 + ar + 64) * EMB + k0 + pnl * 32 + ac, Bs + pb + (tid + 256) * 8);
    }
    __syncthreads();   // drains vmcnt: both panels ready

    #pragma unroll
    for (int pnl = 0; pnl < 2; pnl++) {
      const int pb = pnl * 4096;
      bf16x8 af[4], bfr[4];
      #pragma unroll
      for (int i = 0; i < 4; i++)
        af[i] = asbf(ld8(As + pb + (wm + i * 16 + lm) * 32 + lk));
      #pragma unroll
      for (int j = 0; j < 4; j++)
        bfr[j] = asbf(ld8(Bs + pb + (wn + j * 16 + lm) * 32 + lk));
      #pragma unroll
      for (int i = 0; i < 4; i++)
        #pragma unroll
        for (int j = 0; j < 4; j++)
          acc[i][j] = __builtin_amdgcn_mfma_f32_16x16x32_bf16(af[i], bfr[j], acc[i][j], 0, 0, 0);
    }
  }
}

// LN over the wave's 64-col head span + scatter to bf16 [N, Hdst, L, 64].
__device__ __forceinline__ void epilogue_scatter_ln(
    f32x4 acc[4][4], u16* dst, int m0, int n0, int head_base, int Hdst,
    const float* g, const float* b, int do_ln)
{
  const int lane = threadIdx.x & 63, wave = threadIdx.x >> 6;
  const int wm = (wave >> 1) * 64, wn = (wave & 1) * 64;
  const int lm = lane & 15, quad = lane >> 4;

  float gv[4], bv[4];
  #pragma unroll
  for (int j = 0; j < 4; j++) { gv[j] = g[j * 16 + lm]; bv[j] = b[j * 16 + lm]; }

  #pragma unroll
  for (int i = 0; i < 4; i++)
    #pragma unroll
    for (int r = 0; r < 4; r++) {
      float val[4];
      #pragma unroll
      for (int j = 0; j < 4; j++) val[j] = acc[i][j][r];
      if (do_ln) {
        float s = val[0] + val[1] + val[2] + val[3];
        #pragma unroll
        for (int o = 8; o >= 1; o >>= 1) s += __shfl_xor(s, o, 64);
        float mean = s * (1.f / 64.f);
        float ss = 0.f;
        #pragma unroll
        for (int j = 0; j < 4; j++) { val[j] -= mean; ss += val[j] * val[j]; }
        #pragma unroll
        for (int o = 8; o >= 1; o >>= 1) ss += __shfl_xor(ss, o, 64);
        float inv = rsqrtf(ss * (1.f / 64.f) + 1e-5f);
        #pragma unroll
        for (int j = 0; j < 4; j++) val[j] = val[j] * inv * gv[j] + bv[j];
      }
      int row = m0 + wm + i * 16 + quad * 4 + r;
      int bn = row >> 11, l = row & (SEQ - 1);
      #pragma unroll
      for (int j = 0; j < 4; j++) {
        int col = n0 + wn + j * 16 + lm;
        int hl = (col >> 6) - head_base, d = col & 63;
        dst[(((size_t)(bn * Hdst + hl)) * SEQ + l) * HD + d] = f2b(val[j]);
      }
    }
}

// Merged QKV projection: grid (8, 32, 3).
__global__ __launch_bounds__(256) void gemm_qkv(
    const u16* __restrict__ x,
    const u16* __restrict__ Wq, const u16* __restrict__ Wk, const u16* __restrict__ Wv,
    const float* __restrict__ gq, const float* __restrict__ bq,
    const float* __restrict__ gk, const float* __restrict__ bk,
    u16* __restrict__ qd, u16* __restrict__ kb, u16* __restrict__ vb)
{
  __shared__ __align__(16) u16 As[128 * 64];
  __shared__ __align__(16) u16 Bs[128 * 64];
  const u16* W; u16* dst; const float* g; const float* b; int ln;
  if (blockIdx.z == 0)      { W = Wq; dst = qd; g = gq; b = bq; ln = 1; }
  else if (blockIdx.z == 1) { W = Wk; dst = kb; g = gk; b = bk; ln = 1; }
  else                      { W = Wv; dst = vb; g = gq; b = bq; ln = 0; }
  const int m0 = blockIdx.y * 128, n0 = blockIdx.x * 128;
  f32x4 acc[4][4];
  gemm_acc_128x128<0>(x, W, m0, n0, As, Bs, acc);
  epilogue_scatter_ln(acc, dst, m0, n0, 0, NHEAD, g, b, ln);
}

// Fallback kernels for small-workspace multi-pass K/V.
__global__ __launch_bounds__(256) void gemm_q(
    const u16* __restrict__ x, const u16* __restrict__ Wq,
    const float* __restrict__ gq, const float* __restrict__ bq,
    u16* __restrict__ qd)
{
  __shared__ __align__(16) u16 As[128 * 64];
  __shared__ __align__(16) u16 Bs[128 * 64];
  const int m0 = blockIdx.y * 128, n0 = blockIdx.x * 128;
  f32x4 acc[4][4];
  gemm_acc_128x128<0>(x, Wq, m0, n0, As, Bs, acc);
  epilogue_scatter_ln(acc, qd, m0, n0, 0, NHEAD, gq, bq, 1);
}
__global__ __launch_bounds__(256) void gemm_kv(
    const u16* __restrict__ x,
    const u16* __restrict__ Wk, const u16* __restrict__ Wv,
    const float* __restrict__ gk, const float* __restrict__ bk,
    u16* __restrict__ k, u16* __restrict__ v, int head_lo, int hpp)
{
  __shared__ __align__(16) u16 As[128 * 64];
  __shared__ __align__(16) u16 Bs[128 * 64];
  const int m0 = blockIdx.y * 128, n0 = blockIdx.x * 128;
  const u16* W = (blockIdx.z == 0 ? Wk : Wv) + (size_t)head_lo * HD * EMB;
  u16* dst = (blockIdx.z == 0) ? k : v;
  f32x4 acc[4][4];
  gemm_acc_128x128<0>(x, W, m0, n0, As, Bs, acc);
  epilogue_scatter_ln(acc, dst, m0, n0, 0, hpp, gk, bk, blockIdx.z == 0);
}

// ---------------------------------------------------------------------------
// Flash causal attention — r10 structure VERBATIM (measured optimum).
// grid (16, hpp, NBATCH), block 256.
// ---------------------------------------------------------------------------
__global__ __launch_bounds__(256) void attn(
    u16* qd, const u16* __restrict__ K, const u16* __restrict__ V,
    int head_lo, int hpp)
{
  __shared__ __align__(16) u16 Ks[2][64 * SATT];
  __shared__ __align__(16) u16 Vts[2][64 * 64];     // XOR-swizzled transpose
  __shared__ __align__(16) u16 Ps[4][16 * SATT];    // per-wave P strip

  const int p = blockIdx.x, hl = blockIdx.y, n = blockIdx.z;
  const int qa = p, qb = 31 - p;
  const int tid = threadIdx.x, lane = tid & 63, wave = tid >> 6;
  const int lm = lane & 15, quad = lane >> 4, lk = quad * 8;
  u16* Qh = qd + ((size_t)(n * NHEAD + head_lo + hl)) * SEQ * HD;
  const u16* Kh = K + ((size_t)(n * hpp + hl)) * SEQ * HD;
  const u16* Vh = V + ((size_t)(n * hpp + hl)) * SEQ * HD;

  const int sr = tid >> 3;        // 0..31 (key)
  const int sc = (tid & 7) * 8;   // 0..56 (d base)
  const int vswz = tid & 7;

  bf16x8 aqA[2], aqB[2];
  #pragma unroll
  for (int ks = 0; ks < 2; ++ks) {
    aqA[ks] = asbf(ld8(Qh + (size_t)(qa * 64 + wave * 16 + lm) * HD + ks * 32 + lk));
    aqB[ks] = asbf(ld8(Qh + (size_t)(qb * 64 + wave * 16 + lm) * HD + ks * 32 + lk));
  }

  u16x8 kr0, kr1, vr0, vr1;
  kr0 = ld8(Kh + (size_t)(sr)      * HD + sc);
  kr1 = ld8(Kh + (size_t)(sr + 32) * HD + sc);
  vr0 = ld8(Vh + (size_t)(sr)      * HD + sc);
  vr1 = ld8(Vh + (size_t)(sr + 32) * HD + sc);
  st8(&Ks[0][sr * SATT + sc], kr0);
  st8(&Ks[0][(sr + 32) * SATT + sc], kr1);
  #pragma unroll
  for (int jj = 0; jj < 8; jj++) {
    int d = sc + jj;
    Vts[0][d * 64 + (((sr >> 3) ^ vswz) * 8) + (sr & 7)]        = vr0[jj];
    Vts[0][d * 64 + ((((sr + 32) >> 3) ^ vswz) * 8) + (sr & 7)] = vr1[jj];
  }
  kr0 = ld8(Kh + (size_t)(64 + sr)      * HD + sc);
  kr1 = ld8(Kh + (size_t)(64 + sr + 32) * HD + sc);
  vr0 = ld8(Vh + (size_t)(64 + sr)      * HD + sc);
  vr1 = ld8(Vh + (size_t)(64 + sr + 32) * HD + sc);
  __syncthreads();

  f32x4 oA[4], oB[4];
  float mA[4], psA[4], mB[4], psB[4];
  #pragma unroll
  for (int j = 0; j < 4; j++)
    #pragma unroll
    for (int e = 0; e < 4; e++) { oA[j][e] = 0.f; oB[j][e] = 0.f; }
  #pragma unroll
  for (int r = 0; r < 4; r++) { mA[r] = -1e30f; psA[r] = 0.f; mB[r] = -1e30f; psB[r] = 0.f; }

  u16* Pw = &Ps[wave][0];

  for (int t = 0; t <= qb; ++t) {
    const int cur = t & 1;
    if (t < qb) {
      const int nb = 1 - cur;
      st8(&Ks[nb][sr * SATT + sc], kr0);
      st8(&Ks[nb][(sr + 32) * SATT + sc], kr1);
      #pragma unroll
      for (int jj = 0; jj < 8; jj++) {
        int d = sc + jj;
        Vts[nb][d * 64 + (((sr >> 3) ^ vswz) * 8) + (sr & 7)]        = vr0[jj];
        Vts[nb][d * 64 + ((((sr + 32) >> 3) ^ vswz) * 8) + (sr & 7)] = vr1[jj];
      }
      if (t + 1 < qb) {
        const size_t base = (size_t)(t + 2) * 64;
        kr0 = ld8(Kh + (base + sr)      * HD + sc);
        kr1 = ld8(Kh + (base + sr + 32) * HD + sc);
        vr0 = ld8(Vh + (base + sr)      * HD + sc);
        vr1 = ld8(Vh + (base + sr + 32) * HD + sc);
      }
    }

    #pragma unroll
    for (int tile = 0; tile < 2; ++tile) {
      if (tile == 1 && t > qa) break;
      const int qx = tile ? qa : qb;
      bf16x8* aq = tile ? aqA : aqB;
      f32x4*  oacc = tile ? oA : oB;
      float*  m_i = tile ? mA : mB;
      float*  psum = tile ? psA : psB;

      f32x4 s[4];
      #pragma unroll
      for (int j = 0; j < 4; j++)
        #pragma unroll
        for (int e = 0; e < 4; e++) s[j][e] = 0.f;
      #pragma unroll
      for (int ks = 0; ks < 2; ++ks)
        #pragma unroll
        for (int j = 0; j < 4; j++) {
          bf16x8 bk = asbf(ld8(&Ks[cur][(j * 16 + lm) * SATT + ks * 32 + lk]));
          s[j] = __builtin_amdgcn_mfma_f32_16x16x32_bf16(aq[ks], bk, s[j], 0, 0, 0);
        }
      if (t == qx) {   // causal mask on the diagonal tile
        #pragma unroll
        for (int j = 0; j < 4; j++) {
          int col = t * 64 + j * 16 + lm;
          #pragma unroll
          for (int r = 0; r < 4; r++) {
            int row = qx * 64 + wave * 16 + quad * 4 + r;
            if (col > row) s[j][r] = -1e30f;
          }
        }
      }
      // row max (reduced -> alpha row-uniform); per-lane partial sums only.
      float mnew[4], alpha[4], part[4];
      #pragma unroll
      for (int r = 0; r < 4; r++) {
        float mx = fmaxf(fmaxf(s[0][r], s[1][r]), fmaxf(s[2][r], s[3][r]));
        #pragma unroll
        for (int o = 8; o >= 1; o >>= 1) mx = fmaxf(mx, __shfl_xor(mx, o, 64));
        mnew[r] = fmaxf(m_i[r], mx);
        alpha[r] = __expf(m_i[r] - mnew[r]);
        m_i[r] = mnew[r];
        part[r] = 0.f;
      }
      #pragma unroll
      for (int j = 0; j < 4; j++)
        #pragma unroll
        for (int r = 0; r < 4; r++) {
          float pv = __expf(s[j][r] - mnew[r]);
          s[j][r] = pv;
          part[r] += pv;
        }
      #pragma unroll
      for (int r = 0; r < 4; r++) psum[r] = psum[r] * alpha[r] + part[r];
      #pragma unroll
      for (int j = 0; j < 4; j++)
        #pragma unroll
        for (int r = 0; r < 4; r++) oacc[j][r] *= alpha[r];

      #pragma unroll
      for (int j = 0; j < 4; j++)
        #pragma unroll
        for (int r = 0; r < 4; r++)
          Pw[(quad * 4 + r) * SATT + j * 16 + lm] = f2b(s[j][r]);
      __asm__ __volatile__("" ::: "memory");

      #pragma unroll
      for (int ks = 0; ks < 2; ++ks) {
        bf16x8 ap = asbf(ld8(Pw + lm * SATT + ks * 32 + lk));
        #pragma unroll
        for (int j = 0; j < 4; j++) {
          int dg = 2 * j + (lm >> 3);
          int g  = (ks * 4 + quad) ^ (dg & 7);
          bf16x8 bv = asbf(ld8(&Vts[cur][(j * 16 + lm) * 64 + g * 8]));
          oacc[j] = __builtin_amdgcn_mfma_f32_16x16x32_bf16(ap, bv, oacc[j], 0, 0, 0);
        }
      }
    }
    __syncthreads();   // single per-iteration barrier (dbuf swap)
  }

  // epilogue: reduce the per-lane partial sums (16 lanes per row), write O
  #pragma unroll
  for (int r = 0; r < 4; r++) {
    float sA = psA[r], sB = psB[r];
    #pragma unroll
    for (int o = 8; o >= 1; o >>= 1) { sA += __shfl_xor(sA, o, 64); sB += __shfl_xor(sB, o, 64); }
    float invA = 1.0f / sA, invB = 1.0f / sB;
    int rowA = qa * 64 + wave * 16 + quad * 4 + r;
    int rowB = qb * 64 + wave * 16 + quad * 4 + r;
    #pragma unroll
    for (int j = 0; j < 4; j++) {
      Qh[(size_t)rowB * HD + j * 16 + lm] = f2b(oB[j][r] * invB);
      Qh[(size_t)rowA * HD + j * 16 + lm] = f2b(oA[j][r] * invA);
    }
  }
}

// ---------------------------------------------------------------------------
// Output projection, 64x128 tiles, BK=64 dual-panel: grid (8, 64).
// d_out(f32) = ao @ Wo^T + bo ; ao in [N,16,L,64] bf16.
// ---------------------------------------------------------------------------
__global__ __launch_bounds__(256) void gemm_out(
    const u16* __restrict__ ao, const u16* __restrict__ Wo,
    const float* __restrict__ bo, float* __restrict__ out)
{
  __shared__ __align__(16) u16 As[64 * 64];    // 2 panels of 64x32
  __shared__ __align__(16) u16 Bs[128 * 64];   // 2 panels of 128x32
  const int m0 = blockIdx.y * 64, n0 = blockIdx.x * 128;
  const int tid  = threadIdx.x;
  const int lane = tid & 63;
  const int wave = tid >> 6;
  const int wm   = (wave >> 1) * 32;
  const int wn   = (wave & 1) * 64;
  const int ar   = tid >> 2;        // 0..63
  const int ac   = (tid & 3) * 8;
  const int lm   = lane & 15;
  const int lk   = (lane >> 4) * 8;

  f32x4 acc[2][4];
  #pragma unroll
  for (int i = 0; i < 2; i++)
    #pragma unroll
    for (int j = 0; j < 4; j++)
      #pragma unroll
      for (int e = 0; e < 4; e++) acc[i][j][e] = 0.f;

  for (int k0 = 0; k0 < EMB; k0 += 64) {
    size_t aoff[2];
    #pragma unroll
    for (int pnl = 0; pnl < 2; pnl++) {
      int kc = k0 + pnl * 32 + ac, h = kc >> 6, d = kc & 63;
      int r0 = m0 + ar;
      aoff[pnl] = (((size_t)((r0 >> 11) * NHEAD + h)) * SEQ + (r0 & (SEQ-1))) * HD + d;
    }
    __syncthreads();
    #pragma unroll
    for (int pnl = 0; pnl < 2; pnl++) {
      async_cp16(ao + aoff[pnl], As + pnl * 2048 + tid * 8);
      async_cp16(Wo + (size_t)(n0 + ar)      * EMB + k0 + pnl * 32 + ac, Bs + pnl * 4096 + tid * 8);
      async_cp16(Wo + (size_t)(n0 + ar + 64) * EMB + k0 + pnl * 32 + ac, Bs + pnl * 4096 + (tid + 256) * 8);
    }
    __syncthreads();

    #pragma unroll
    for (int pnl = 0; pnl < 2; pnl++) {
      bf16x8 af[2], bfr[4];
      #pragma unroll
      for (int i = 0; i < 2; i++)
        af[i] = asbf(ld8(As + pnl * 2048 + (wm + i * 16 + lm) * 32 + lk));
      #pragma unroll
      for (int j = 0; j < 4; j++)
        bfr[j] = asbf(ld8(Bs + pnl * 4096 + (wn + j * 16 + lm) * 32 + lk));
      #pragma unroll
      for (int i = 0; i < 2; i++)
        #pragma unroll
        for (int j = 0; j < 4; j++)
          acc[i][j] = __builtin_amdgcn_mfma_f32_16x16x32_bf16(af[i], bfr[j], acc[i][j], 0, 0, 0);
    }
  }

  const int quad = lane >> 4;
  #pragma unroll
  for (int j = 0; j < 4; j++) {
    int col = n0 + wn + j * 16 + lm;
    float bias = bo[col];
    #pragma unroll
    for (int i = 0; i < 2; i++)
      #pragma unroll
      for (int r = 0; r < 4; r++) {
        int row = m0 + wm + i * 16 + quad * 4 + r;
        out[(size_t)row * EMB + col] = acc[i][j][r] + bias;
      }
  }
}

extern "C" void kernel_launch(void* const* d_in, const int* in_sizes, int n_in,
                              void* d_out, int out_size, void* d_ws, size_t ws_size,
                              hipStream_t stream)
{
  const float* xf  = (const float*)d_in[0];
  const float* Wqf = (const float*)d_in[2];
  const float* Wkf = (const float*)d_in[3];
  const float* Wvf = (const float*)d_in[4];
  const float* gq  = (const float*)d_in[5];
  const float* bq  = (const float*)d_in[6];
  const float* gk  = (const float*)d_in[7];
  const float* bk  = (const float*)d_in[8];
  const float* Wof = (const float*)d_in[9];
  const float* bo  = (const float*)d_in[10];

  const size_t MB = 1u << 20;
  u16* xb  = (u16*)d_ws;                           // 8 MiB
  u16* wqb = xb  + (size_t)ROWS * EMB;             // 2 MiB each
  u16* wkb = wqb + (size_t)EMB * EMB;
  u16* wvb = wkb + (size_t)EMB * EMB;
  u16* wob = wvb + (size_t)EMB * EMB;
  u16* kvbase = wob + (size_t)EMB * EMB;           // ws + 16 MiB

  size_t avail = (ws_size > 16 * MB) ? ws_size - 16 * MB : 2 * MB;
  int hpp = NHEAD;
  while ((size_t)hpp * MB > avail && hpp > 2) hpp >>= 1;
  const size_t kv_elems = (size_t)hpp * NBATCH * SEQ * HD;
  u16* kbuf = kvbase;
  u16* vbuf = kbuf + kv_elems;

  // Q (bf16, + in-place attn output) lives in the x input buffer (dead
  // after cvt_all). gemm_out writes f32 straight to d_out.
  u16* qd = (u16*)d_in[0];
  float* out = (float*)d_out;

  cvt_all<<<dim3(8192), 256, 0, stream>>>(xf, Wqf, Wkf, Wvf, Wof,
                                          xb, wqb, wkb, wvb, wob);
  if (hpp == NHEAD) {
    gemm_qkv<<<dim3(8, 32, 3), 256, 0, stream>>>(xb, wqb, wkb, wvb,
                                                 gq, bq, gk, bk,
                                                 qd, kbuf, vbuf);
    attn<<<dim3(16, NHEAD, NBATCH), 256, 0, stream>>>(qd, kbuf, vbuf, 0, NHEAD);
  } else {
    gemm_q<<<dim3(8, 32), 256, 0, stream>>>(xb, wqb, gq, bq, qd);
    for (int g = 0; g < NHEAD / hpp; ++g) {
      gemm_kv<<<dim3(hpp / 2, 32, 2), 256, 0, stream>>>(xb, wkb, wvb, gk, bk,
                                                        kbuf, vbuf, g * hpp, hpp);
      attn<<<dim3(16, hpp, NBATCH), 256, 0, stream>>>(qd, kbuf, vbuf, g * hpp, hpp);
    }
  }
  gemm_out<<<dim3(8, 64), 256, 0, stream>>>(qd, wob, bo, out);
}